// Round 1
// 387.983 us; speedup vs baseline: 1.0561x; 1.0561x over previous
//
#include <hip/hip_runtime.h>
#include <hip/hip_bf16.h>

// Problem constants
#define S_LEN   1024
#define BATCH   4
#define DMODEL  2048
#define NHEADS  16
#define NKVH    8
#define HEADD   128
#define NTOK    4096      // BATCH*S_LEN
#define QKV_CH  4096      // 2048 q + 1024 k + 1024 v

typedef __bf16 bf16x8 __attribute__((ext_vector_type(8)));
typedef float  f32x4  __attribute__((ext_vector_type(4)));

__device__ __forceinline__ float bf2f(unsigned short u) {
    return __uint_as_float(((unsigned)u) << 16);
}
__device__ __forceinline__ ushort f2bu(float f) {
    union { __hip_bfloat16 h; ushort u; } c;
    c.h = __float2bfloat16(f);
    return c.u;
}
// async global->LDS, 16B per lane; LDS dest must be wave-contiguous in lane order
__device__ __forceinline__ void gl_lds16(const ushort* g, ushort* l) {
    __builtin_amdgcn_global_load_lds(
        (const __attribute__((address_space(1))) void*)g,
        (__attribute__((address_space(3))) void*)l,
        16, 0, 0);
}

// ---------------- fused weight casts: Wq/Wk/Wv/Wo/lA fp32 -> bf16 ----------------
__global__ __launch_bounds__(256) void wcast_kernel(const float* __restrict__ Wq,
                                                    const float* __restrict__ Wk,
                                                    const float* __restrict__ Wv,
                                                    const float* __restrict__ Wo,
                                                    const float* __restrict__ lA,
                                                    __hip_bfloat16* __restrict__ wqkv,
                                                    __hip_bfloat16* __restrict__ wo,
                                                    __hip_bfloat16* __restrict__ acat) {
    int i = blockIdx.x * 256 + threadIdx.x;
    const float* src; __hip_bfloat16* dst; int off;
    if (i < 1048576)      { src = Wq; dst = wqkv;           off = i; }
    else if (i < 1572864) { src = Wk; dst = wqkv + 4194304; off = i - 1048576; }
    else if (i < 2097152) { src = Wv; dst = wqkv + 6291456; off = i - 1572864; }
    else if (i < 3145728) { src = Wo; dst = wo;             off = i - 2097152; }
    else if (i < 3178496) { src = lA; dst = acat;           off = i - 3145728; }
    else return;
    float4 v = ((const float4*)src)[off];
    union { ushort4 u; __hip_bfloat16 h[4]; } r;
    r.h[0] = __float2bfloat16(v.x);
    r.h[1] = __float2bfloat16(v.y);
    r.h[2] = __float2bfloat16(v.z);
    r.h[3] = __float2bfloat16(v.w);
    ((ushort4*)dst)[off] = r.u;
}

// ---------------- lB (e,d,r) fp32 -> Bt[d][e*16+r] bf16 ----------------
__global__ __launch_bounds__(256) void btrans_kernel(const float* __restrict__ lB,
                                                     ushort* __restrict__ Bt) {
    int idx = blockIdx.x * 256 + threadIdx.x;   // 131072
    int d = idx >> 6, er = idx & 63;
    int e = er >> 4, r = er & 15;
    Bt[idx] = f2bu(lB[((size_t)e * DMODEL + d) * 16 + r]);
}

// ---------------- fused hidden cast + gate (block = one token) ----------------
__global__ __launch_bounds__(256) void gatecast_kernel(const float* __restrict__ X,
                                                       const float* __restrict__ GW,
                                                       __hip_bfloat16* __restrict__ Xb,
                                                       float* __restrict__ EW) {
    __shared__ float red[4][257];
    const int t = blockIdx.x, tid = threadIdx.x;
    const float* x = X + (size_t)t * DMODEL;
    __hip_bfloat16* xb = Xb + (size_t)t * DMODEL;
    float p0 = 0.f, p1 = 0.f, p2 = 0.f, p3 = 0.f;
#pragma unroll
    for (int c = 0; c < 2; c++) {
        int i4 = tid + c * 256;           // float4 group in row
        float4 v = ((const float4*)x)[i4];
        union { ushort4 u; __hip_bfloat16 h[4]; } r;
        r.h[0] = __float2bfloat16(v.x);
        r.h[1] = __float2bfloat16(v.y);
        r.h[2] = __float2bfloat16(v.z);
        r.h[3] = __float2bfloat16(v.w);
        ((ushort4*)xb)[i4] = r.u;
        int d = i4 * 4;
        const float* g0 = GW + d;
        p0 += v.x * g0[0] + v.y * g0[1] + v.z * g0[2] + v.w * g0[3];
        const float* g1 = GW + DMODEL + d;
        p1 += v.x * g1[0] + v.y * g1[1] + v.z * g1[2] + v.w * g1[3];
        const float* g2 = GW + 2 * DMODEL + d;
        p2 += v.x * g2[0] + v.y * g2[1] + v.z * g2[2] + v.w * g2[3];
        const float* g3 = GW + 3 * DMODEL + d;
        p3 += v.x * g3[0] + v.y * g3[1] + v.z * g3[2] + v.w * g3[3];
    }
    red[0][tid] = p0; red[1][tid] = p1; red[2][tid] = p2; red[3][tid] = p3;
    __syncthreads();
    for (int s = 128; s > 0; s >>= 1) {
        if (tid < s) {
            red[0][tid] += red[0][tid + s];
            red[1][tid] += red[1][tid + s];
            red[2][tid] += red[2][tid + s];
            red[3][tid] += red[3][tid + s];
        }
        __syncthreads();
    }
    if (tid == 0) {
        float l[4] = { red[0][0], red[1][0], red[2][0], red[3][0] };
        float mx = fmaxf(fmaxf(l[0], l[1]), fmaxf(l[2], l[3]));
        float pe[4], sum = 0.f;
        for (int e = 0; e < 4; e++) { pe[e] = __expf(l[e] - mx); sum += pe[e]; }
        float inv = 1.0f / sum;
        for (int e = 0; e < 4; e++) pe[e] *= inv;
        int i1 = 0;
        for (int e = 1; e < 4; e++) if (pe[e] > pe[i1]) i1 = e;
        int i2 = -1;
        for (int e = 0; e < 4; e++) if (e != i1 && (i2 < 0 || pe[e] > pe[i2])) i2 = e;
        float o[4] = {0.f, 0.f, 0.f, 0.f};
        o[i1] = pe[i1]; o[i2] = pe[i2];
        float* ew = EW + (size_t)t * 4;
        ew[0] = o[0]; ew[1] = o[1]; ew[2] = o[2]; ew[3] = o[3];
    }
}

// =====================================================================================
// 256x256 8-phase bf16 GEMM (T2 swizzle + T3/T4 counted vmcnt + T5 setprio)
// C[M][N] = A[M][K] * B[N][K]^T, fp32 C. 512 threads = 8 waves (2M x 4N), BK=64.
// LDS 128 KiB: [buf0-A | buf0-B | buf1-A | buf1-B], each 256x64 bf16, XOR-swizzled:
//   element (row,col) lives at ushort offset row*64 + (col ^ ((row&7)<<3)).
// Staged via global_load_lds with linear LDS dest + inverse-swizzled GLOBAL source.
// Wave wm covers A-rows {ii*32 + wm*16 .. +16} per half (interleaved), wave wn covers
// B-rows (C-cols) {jj*64 + wn*16} per half — so each phase (QM,QN) reads exactly one
// A-half and one B-half, making the stage schedule provably WAR-safe at barriers.
// =====================================================================================
#define LDSA0 0
#define LDSB0 16384
#define LDSA1 32768
#define LDSB1 49152

#define FENCE_BAR() do { asm volatile("" ::: "memory"); __builtin_amdgcn_s_barrier(); } while (0)

__device__ __forceinline__ void stage_half(const ushort* src, ushort* dst, int ld) {
    // half-tile = 128 rows x 64 cols bf16 = 16 KB = 2 x (512 lanes x 16 B)
    gl_lds16(src, dst);
    gl_lds16(src + (size_t)64 * ld, dst + 4096);
}

template<int QM, int QN>
__device__ __forceinline__ void phase8(const ushort* As, const ushort* Bs,
                                       f32x4 (&acc)[8][4],
                                       int aBase, int bBase, int cs0, int cs1,
                                       const ushort* sSrc, ushort* sDst, int sLd, bool sEn)
{
    bf16x8 af[4][2], bf[2][2];
#pragma unroll
    for (int ii = 0; ii < 4; ii++) {
        af[ii][0] = *(const bf16x8*)(As + aBase + QM * 8192 + ii * 2048 + cs0);
        af[ii][1] = *(const bf16x8*)(As + aBase + QM * 8192 + ii * 2048 + cs1);
    }
#pragma unroll
    for (int jj = 0; jj < 2; jj++) {
        bf[jj][0] = *(const bf16x8*)(Bs + bBase + QN * 8192 + jj * 4096 + cs0);
        bf[jj][1] = *(const bf16x8*)(Bs + bBase + QN * 8192 + jj * 4096 + cs1);
    }
    if (sEn) stage_half(sSrc, sDst, sLd);
    asm volatile("" ::: "memory");
    __builtin_amdgcn_s_barrier();
    asm volatile("s_waitcnt lgkmcnt(0)" ::: "memory");
    __builtin_amdgcn_sched_barrier(0);
    __builtin_amdgcn_s_setprio(1);
#pragma unroll
    for (int k = 0; k < 2; k++)
#pragma unroll
        for (int ii = 0; ii < 4; ii++)
#pragma unroll
            for (int jj = 0; jj < 2; jj++)
                acc[QM * 4 + ii][QN + 2 * jj] = __builtin_amdgcn_mfma_f32_16x16x32_bf16(
                    af[ii][k], bf[jj][k], acc[QM * 4 + ii][QN + 2 * jj], 0, 0, 0);
    __builtin_amdgcn_s_setprio(0);
    // caller emits [vmcnt] + fence + s_barrier
}

__global__ __launch_bounds__(512, 2) void gemm256(const ushort* __restrict__ A,
                                                  const ushort* __restrict__ B,
                                                  float* __restrict__ C,
                                                  int M, int N, int K) {
    __shared__ __align__(16) ushort lds[65536];   // 128 KiB
    const int tid  = threadIdx.x;
    const int wave = tid >> 6, lane = tid & 63;
    const int l16  = lane & 15, quad = lane >> 4;
    const int wm = wave >> 2, wn = wave & 3;
    const int m0 = blockIdx.y * 256, n0 = blockIdx.x * 256;

    // stage-source constants: thread tid fills LDS ushorts [tid*8, tid*8+8) of a half,
    // i.e. local row tid>>3, swizzled col -> read from inverse-swizzled global col.
    const int srow = tid >> 3;
    const int scol = ((tid & 7) * 8) ^ ((srow & 7) << 3);
    const ushort* aSrc = A + (size_t)(m0 + srow) * K + scol;
    const ushort* bSrc = B + (size_t)(n0 + srow) * K + scol;

    // ds_read constants: row = (frag base)+l16; swizzled col = ((k*4+quad)^(l16&7))*8
    const int aBase = (wm * 16 + l16) * 64;
    const int bBase = (wn * 16 + l16) * 64;
    const int cs0 = ((0 + quad) ^ (l16 & 7)) * 8;
    const int cs1 = ((4 + quad) ^ (l16 & 7)) * 8;

    f32x4 acc[8][4];
#pragma unroll
    for (int i = 0; i < 8; i++)
#pragma unroll
        for (int j = 0; j < 4; j++) acc[i][j] = (f32x4){0.f, 0.f, 0.f, 0.f};

    const int NT = K >> 6;   // K-tiles of 64

    const ushort* A0s = lds + LDSA0;
    const ushort* B0s = lds + LDSB0;
    const ushort* A1s = lds + LDSA1;
    const ushort* B1s = lds + LDSB1;

    // prologue: tile0 fully -> buf0 (8 loads), tile1 halves A0,B0 -> buf1 (4 loads)
    stage_half(aSrc,                     lds + LDSA0 + tid * 8, K);
    stage_half(aSrc + (size_t)128 * K,   lds + LDSA0 + 8192 + tid * 8, K);
    stage_half(bSrc,                     lds + LDSB0 + tid * 8, K);
    stage_half(bSrc + (size_t)128 * K,   lds + LDSB0 + 8192 + tid * 8, K);
    stage_half(aSrc + 64,                lds + LDSA1 + tid * 8, K);
    stage_half(bSrc + 64,                lds + LDSB1 + tid * 8, K);
    asm volatile("s_waitcnt vmcnt(4)" ::: "memory");   // tile0 resident; tile1 in flight
    __builtin_amdgcn_s_barrier();

    for (int t = 0; t + 1 < NT; t += 2) {
        const bool s34 = (t + 2) < NT, s78 = (t + 3) < NT;
        const int k1 = (t + 1) * 64, k2 = (t + 2) * 64, k3 = (t + 3) * 64;

        // P1: buf0 quad(0,0); stage A-h1(t+1)->buf1  (buf1-A1 last read prev P8)
        phase8<0, 0>(A0s, B0s, acc, aBase, bBase, cs0, cs1,
                     aSrc + (size_t)128 * K + k1, lds + LDSA1 + 8192 + tid * 8, K, true);
        FENCE_BAR();
        // P2: (0,1); stage B-h1(t+1)->buf1
        phase8<0, 1>(A0s, B0s, acc, aBase, bBase, cs0, cs1,
                     bSrc + (size_t)128 * K + k1, lds + LDSB1 + 8192 + tid * 8, K, true);
        FENCE_BAR();
        // P3: (1,0); stage A-h0(t+2)->buf0  (buf0-A0 last read P2)
        phase8<1, 0>(A0s, B0s, acc, aBase, bBase, cs0, cs1,
                     aSrc + k2, lds + LDSA0 + tid * 8, K, s34);
        FENCE_BAR();
        // P4: (1,1); stage B-h0(t+2)->buf0; counted wait: tile t+1 resident,
        // P3/P4's loads (4) may stay in flight
        phase8<1, 1>(A0s, B0s, acc, aBase, bBase, cs0, cs1,
                     bSrc + k2, lds + LDSB0 + tid * 8, K, s34);
        if (s34) { asm volatile("s_waitcnt vmcnt(4)" ::: "memory"); }
        else     { asm volatile("s_waitcnt vmcnt(0)" ::: "memory"); }
        __builtin_amdgcn_s_barrier();
        // P5: buf1 (0,0); stage A-h1(t+2)->buf0
        phase8<0, 0>(A1s, B1s, acc, aBase, bBase, cs0, cs1,
                     aSrc + (size_t)128 * K + k2, lds + LDSA0 + 8192 + tid * 8, K, s34);
        FENCE_BAR();
        // P6: (0,1); stage B-h1(t+2)->buf0
        phase8<0, 1>(A1s, B1s, acc, aBase, bBase, cs0, cs1,
                     bSrc + (size_t)128 * K + k2, lds + LDSB0 + 8192 + tid * 8, K, s34);
        FENCE_BAR();
        // P7: (1,0); stage A-h0(t+3)->buf1  (buf1-A0 last read P6)
        phase8<1, 0>(A1s, B1s, acc, aBase, bBase, cs0, cs1,
                     aSrc + k3, lds + LDSA1 + tid * 8, K, s78);
        FENCE_BAR();
        // P8: (1,1); stage B-h0(t+3)->buf1; counted wait: tile t+2 resident
        phase8<1, 1>(A1s, B1s, acc, aBase, bBase, cs0, cs1,
                     bSrc + k3, lds + LDSB1 + tid * 8, K, s78);
        if (s78) { asm volatile("s_waitcnt vmcnt(4)" ::: "memory"); }
        else     { asm volatile("s_waitcnt vmcnt(0)" ::: "memory"); }
        __builtin_amdgcn_s_barrier();
    }
    // NT even here (K=2048 -> 32 tiles): no tail tile.

    // epilogue: C[m0 + (i&3)*32 + wm*16 + (i>>2)*128 + quad*4 + r]
    //            [n0 + (j&1)*128 + (j>>1)*64 + wn*16 + l16]
    float* crow = C + (size_t)(m0 + wm * 16 + quad * 4) * N + n0 + wn * 16 + l16;
#pragma unroll
    for (int i = 0; i < 8; i++) {
        float* cpi = crow + (size_t)((i & 3) * 32 + (i >> 2) * 128) * N;
#pragma unroll
        for (int r = 0; r < 4; r++)
#pragma unroll
            for (int j = 0; j < 4; j++)
                cpi[(size_t)r * N + ((j & 1) * 128 + (j >> 1) * 64)] = acc[i][j][r];
    }
}

// ---------------- Wo GEMM with fused LoRA delta: C = A*B^T + A2*B2^T (fp32 out) ----------------
__global__ __launch_bounds__(256) void gemm_bt_lora(const ushort* __restrict__ A,
                                                    const ushort* __restrict__ B,
                                                    const ushort* __restrict__ A2,
                                                    const ushort* __restrict__ B2,
                                                    float* __restrict__ C) {
    __shared__ ushort As[128 * 32];
    __shared__ ushort Bs[128 * 32];
    const int tid  = threadIdx.x;
    const int wave = tid >> 6, lane = tid & 63;
    const int l16  = lane & 15, quad = lane >> 4;
    const int m0 = blockIdx.y * 128, n0 = blockIdx.x * 128;
    const int wm = (wave >> 1) * 64, wn = (wave & 1) * 64;
    const int K = DMODEL, N = DMODEL;

    f32x4 acc[4][4];
#pragma unroll
    for (int i = 0; i < 4; i++)
#pragma unroll
        for (int j = 0; j < 4; j++) acc[i][j] = (f32x4){0.f, 0.f, 0.f, 0.f};

    const int r1 = tid >> 2, kg1 = (tid & 3) * 8;
    const int r2 = (tid + 256) >> 2, kg2 = ((tid + 256) & 3) * 8;

    for (int k0 = 0; k0 < K; k0 += 32) {
        __syncthreads();
        gl_lds16(A + (size_t)(m0 + r1) * K + k0 + kg1, As + tid * 8);
        gl_lds16(B + (size_t)(n0 + r1) * K + k0 + kg1, Bs + tid * 8);
        gl_lds16(A + (size_t)(m0 + r2) * K + k0 + kg2, As + (tid + 256) * 8);
        gl_lds16(B + (size_t)(n0 + r2) * K + k0 + kg2, Bs + (tid + 256) * 8);
        __syncthreads();
        bf16x8 af[4], bfr[4];
#pragma unroll
        for (int i = 0; i < 4; i++) {
            af[i]  = *(const bf16x8*)(As + (wm + i * 16 + l16) * 32 + quad * 8);
            bfr[i] = *(const bf16x8*)(Bs + (wn + i * 16 + l16) * 32 + quad * 8);
        }
#pragma unroll
        for (int i = 0; i < 4; i++)
#pragma unroll
            for (int j = 0; j < 4; j++)
                acc[i][j] = __builtin_amdgcn_mfma_f32_16x16x32_bf16(af[i], bfr[j], acc[i][j], 0, 0, 0);
    }

    // LoRA delta: 2 extra K-steps over K2=64
#pragma unroll
    for (int k0 = 0; k0 < 64; k0 += 32) {
        __syncthreads();
        gl_lds16(A2 + (size_t)(m0 + r1) * 64 + k0 + kg1, As + tid * 8);
        gl_lds16(B2 + (size_t)(n0 + r1) * 64 + k0 + kg1, Bs + tid * 8);
        gl_lds16(A2 + (size_t)(m0 + r2) * 64 + k0 + kg2, As + (tid + 256) * 8);
        gl_lds16(B2 + (size_t)(n0 + r2) * 64 + k0 + kg2, Bs + (tid + 256) * 8);
        __syncthreads();
        bf16x8 af[4], bfr[4];
#pragma unroll
        for (int i = 0; i < 4; i++) {
            af[i]  = *(const bf16x8*)(As + (wm + i * 16 + l16) * 32 + quad * 8);
            bfr[i] = *(const bf16x8*)(Bs + (wn + i * 16 + l16) * 32 + quad * 8);
        }
#pragma unroll
        for (int i = 0; i < 4; i++)
#pragma unroll
            for (int j = 0; j < 4; j++)
                acc[i][j] = __builtin_amdgcn_mfma_f32_16x16x32_bf16(af[i], bfr[j], acc[i][j], 0, 0, 0);
    }

#pragma unroll
    for (int i = 0; i < 4; i++)
#pragma unroll
        for (int j = 0; j < 4; j++)
#pragma unroll
            for (int r = 0; r < 4; r++) {
                int m = m0 + wm + i * 16 + quad * 4 + r;
                int n = n0 + wn + j * 16 + l16;
                C[(size_t)m * N + n] = acc[i][j][r];
            }
}

// ---------------- LoRA H: G[t][e*16+r] = bf16(2*ew[t][e] * (x_t . A[e][r])) ----------------
__global__ __launch_bounds__(256) void lora_h_kernel(const ushort* __restrict__ X,
                                                     const ushort* __restrict__ Acat,
                                                     const float* __restrict__ EW,
                                                     ushort* __restrict__ G) {
    __shared__ ushort As[64 * 32];
    __shared__ ushort Bs[64 * 32];
    const int tid = threadIdx.x;
    const int wave = tid >> 6, lane = tid & 63;
    const int l16 = lane & 15, quad = lane >> 4;
    const int m0 = blockIdx.x * 64;

    f32x4 acc[4];
#pragma unroll
    for (int nt = 0; nt < 4; nt++) acc[nt] = (f32x4){0.f, 0.f, 0.f, 0.f};

    const int r1 = tid >> 2, kg1 = (tid & 3) * 8;

    for (int k0 = 0; k0 < DMODEL; k0 += 32) {
        __syncthreads();
        gl_lds16(X + (size_t)(m0 + r1) * DMODEL + k0 + kg1, As + tid * 8);
        gl_lds16(Acat + (size_t)r1 * DMODEL + k0 + kg1, Bs + tid * 8);
        __syncthreads();
        bf16x8 af = *(const bf16x8*)(As + (wave * 16 + l16) * 32 + quad * 8);
#pragma unroll
        for (int nt = 0; nt < 4; nt++) {
            bf16x8 bfr = *(const bf16x8*)(Bs + (nt * 16 + l16) * 32 + quad * 8);
            acc[nt] = __builtin_amdgcn_mfma_f32_16x16x32_bf16(af, bfr, acc[nt], 0, 0, 0);
        }
    }
#pragma unroll
    for (int nt = 0; nt < 4; nt++)
#pragma unroll
        for (int r = 0; r < 4; r++) {
            int m = m0 + wave * 16 + quad * 4 + r;
            float wsc = 2.0f * EW[(size_t)m * 4 + nt];   // LORA_SCALE=2 folded
            G[(size_t)m * 64 + nt * 16 + l16] = f2bu(acc[nt][r] * wsc);
        }
}

// ---------------- RMSNorm + RoPE: fp32 qkv -> bf16 Qb[b,h,s,d] (scaled), Kb[b,kv,s,d] ----------------
__global__ __launch_bounds__(256) void normrope_kernel(const float* __restrict__ QKV,
                                                       const float* __restrict__ cosb,
                                                       const float* __restrict__ sinb,
                                                       const float* __restrict__ qw,
                                                       const float* __restrict__ kw,
                                                       ushort* __restrict__ Qb,
                                                       ushort* __restrict__ Kb) {
    const int wave = threadIdx.x >> 6, lane = threadIdx.x & 63;
    const int r = blockIdx.x * 4 + wave;
    const float* p; const float* w; int t; ushort* dst; float scale;
    if (r < NTOK * NHEADS) {
        t = r >> 4;
        int h = r & 15;
        p = QKV + (size_t)t * QKV_CH + h * HEADD;
        w = qw; scale = 0.08838834764831845f;   // 128^-0.5 folded into Q
        int b = t >> 10, s = t & 1023;
        dst = Qb + ((size_t)((b * 16 + h) * 1024 + s)) * HEADD;
    } else {
        int r2 = r - NTOK * NHEADS;
        t = r2 >> 3;
        int kv = r2 & 7;
        p = QKV + (size_t)t * QKV_CH + 2048 + kv * HEADD;
        w = kw; scale = 1.0f;
        int b = t >> 10, s = t & 1023;
        dst = Kb + ((size_t)((b * 8 + kv) * 1024 + s)) * HEADD;
    }
    float xl = p[lane], xh = p[lane + 64];
    float ss = xl * xl + xh * xh;
#pragma unroll
    for (int mask = 1; mask < 64; mask <<= 1) ss += __shfl_xor(ss, mask);
    float rstd = rsqrtf(ss * (1.0f / 128.0f) + 1e-6f);
    float nl = xl * rstd * w[lane];
    float nh = xh * rstd * w[lane + 64];
    const float* cp = cosb + (size_t)t * HEADD;
    const float* sp = sinb + (size_t)t * HEADD;
    float ol = nl * cp[lane]      - nh * sp[lane];
    float oh = nh * cp[lane + 64] + nl * sp[lane + 64];
    dst[lane]      = f2bu(ol * scale);
    dst[lane + 64] = f2bu(oh * scale);
}

// ---------------- V transpose: fp32 qkv v -> bf16 Vt[b,kv,d,s] ----------------
__global__ __launch_bounds__(256) void vtrans_kernel(const float* __restrict__ QKV,
                                                     ushort* __restrict__ Vt) {
    __shared__ float Ts[64][129];
    const int blk = blockIdx.x;          // 4*8*16
    const int sc = blk & 15;
    const int kvb = blk >> 4;            // b*8+kv
    const int s0 = sc * 64;
    const float* src = QKV + ((size_t)((kvb >> 3) * 1024 + s0)) * QKV_CH + 3072 + (kvb & 7) * HEADD;
    for (int c = threadIdx.x; c < 2048; c += 256) {
        int s = c >> 5, d0 = (c & 31) * 4;
        float4 v = *(const float4*)(src + (size_t)s * QKV_CH + d0);
        Ts[s][d0] = v.x; Ts[s][d0 + 1] = v.y; Ts[s][d0 + 2] = v.z; Ts[s][d0 + 3] = v.w;
    }
    __syncthreads();
    ushort* dst = Vt + ((size_t)kvb * HEADD) * S_LEN + s0;
    for (int c = threadIdx.x; c < 1024; c += 256) {
        int d = c >> 3, s8 = (c & 7) * 8;
        union { ushort u[8]; uint4 v; } pk;
#pragma unroll
        for (int j = 0; j < 8; j++) pk.u[j] = f2bu(Ts[s8 + j][d]);
        *(uint4*)(dst + (size_t)d * S_LEN + s8) = pk.v;
    }
}

// ---------------- flash attention (bf16 MFMA, no-max softmax — exact by boundedness) ----------------
// |q|=|k|=sqrt(128) after rmsnorm, scale 1/sqrt(128) => |s|<=11.4, exp(s)<=9e4: fp32/bf16 safe.
#define KPITCH 136
#define VPITCH 72
__global__ __launch_bounds__(256) void fattn_kernel(const ushort* __restrict__ Qb,
                                                    const ushort* __restrict__ Kb,
                                                    const ushort* __restrict__ Vt,
                                                    __hip_bfloat16* __restrict__ O) {
    __shared__ __align__(16) ushort Ks[64 * KPITCH];
    __shared__ __align__(16) ushort Vs[128 * VPITCH];
    __shared__ __align__(16) ushort Ps[4 * 16 * VPITCH];
    const int tid = threadIdx.x;
    const int wq = tid >> 6, lane = tid & 63;
    const int l16 = lane & 15, quad = lane >> 4;
    const int qblk = 15 - (blockIdx.x >> 6);    // heavy q-blocks first
    const int bh = blockIdx.x & 63;
    const int b = bh >> 4, h = bh & 15;
    const int kvb = b * 8 + (h >> 1);
    const int q0 = qblk * 64;
    const int qbase = q0 + wq * 16;

    bf16x8 qf[4];
    const ushort* qrow = Qb + ((size_t)bh * S_LEN + qbase + l16) * HEADD;
#pragma unroll
    for (int kt = 0; kt < 4; kt++)
        qf[kt] = *(const bf16x8*)(qrow + kt * 32 + quad * 8);

    f32x4 oacc[8];
#pragma unroll
    for (int dt = 0; dt < 8; dt++) oacc[dt] = (f32x4){0.f, 0.f, 0.f, 0.f};
    float l[4] = { 0.f, 0.f, 0.f, 0.f };   // per-lane partial denominators

    const ushort* kbase = Kb + (size_t)kvb * S_LEN * HEADD;
    const ushort* vbase = Vt + (size_t)kvb * HEADD * S_LEN;
    const int ntiles = qblk + 1;

    for (int kb = 0; kb < ntiles; kb++) {
        const int k0 = kb * 64;
        __syncthreads();
        for (int c = tid; c < 1024; c += 256) {
            int row = c >> 4, col = (c & 15) * 8;
            *(uint4*)(Ks + row * KPITCH + col) =
                *(const uint4*)(kbase + (size_t)(k0 + row) * HEADD + col);
        }
        for (int c = tid; c < 1024; c += 256) {
            int row = c >> 3, col = (c & 7) * 8;
            *(uint4*)(Vs + row * VPITCH + col) =
                *(const uint4*)(vbase + (size_t)row * S_LEN + k0 + col);
        }
        __syncthreads();

        f32x4 sacc[4];
#pragma unroll
        for (int nt = 0; nt < 4; nt++) sacc[nt] = (f32x4){0.f, 0.f, 0.f, 0.f};
#pragma unroll
        for (int kt = 0; kt < 4; kt++) {
#pragma unroll
            for (int nt = 0; nt < 4; nt++) {
                bf16x8 kf = *(const bf16x8*)(Ks + (nt * 16 + l16) * KPITCH + kt * 32 + quad * 8);
                sacc[nt] = __builtin_amdgcn_mfma_f32_16x16x32_bf16(qf[kt], kf, sacc[nt], 0, 0, 0);
            }
        }

        // p = exp(s) (no max subtraction), causal mask, accumulate partial l
#pragma unroll
        for (int r = 0; r < 4; r++) {
            const int qg = qbase + quad * 4 + r;
#pragma unroll
            for (int nt = 0; nt < 4; nt++) {
                int kg = k0 + nt * 16 + l16;
                float p = (kg <= qg) ? __expf(sacc[nt][r]) : 0.f;
                l[r] += p;
                Ps[wq * 16 * VPITCH + (quad * 4 + r) * VPITCH + nt * 16 + l16] = f2bu(p);
            }
        }

        // O += P V (unnormalized, no rescale needed)
#pragma unroll
        for (int kt2 = 0; kt2 < 2; kt2++) {
            bf16x8 pf = *(const bf16x8*)(Ps + wq * 16 * VPITCH + l16 * VPITCH + kt2 * 32 + quad * 8);
#pragma unroll
            for (int dt = 0; dt < 8; dt++) {
                bf16x8 vf = *(const bf16x8*)(Vs + (dt * 16 + l16) * VPITCH + kt2 * 32 + quad * 8);
                oacc[dt] = __builtin_amdgcn_mfma_f32_16x16x32_bf16(pf, vf, oacc[dt], 0, 0, 0);
            }
        }
    }

    // epilogue: reduce l across the 16-lane key groups, normalize, store
#pragma unroll
    for (int r = 0; r < 4; r++) {
        float lr = l[r];
        lr += __shfl_xor(lr, 1);
        lr += __shfl_xor(lr, 2);
        lr += __shfl_xor(lr, 4);
        lr += __shfl_xor(lr, 8);
        float inv = 1.0f / lr;
        size_t base = ((size_t)(b * S_LEN + qbase + quad * 4 + r)) * (NHEADS * HEADD) + h * HEADD;
#pragma unroll
        for (int dt = 0; dt < 8; dt++)
            O[base + dt * 16 + l16] = __float2bfloat16(oacc[dt][r] * inv);
    }
}

extern "C" void kernel_launch(void* const* d_in, const int* in_sizes, int n_in,
                              void* d_out, int out_size, void* d_ws, size_t ws_size,
                              hipStream_t stream) {
    const float* hidden = (const float*)d_in[0];
    const float* cosb   = (const float*)d_in[1];
    const float* sinb   = (const float*)d_in[2];
    const float* Wq     = (const float*)d_in[3];
    const float* Wk     = (const float*)d_in[4];
    const float* Wv     = (const float*)d_in[5];
    const float* Wo     = (const float*)d_in[6];
    const float* qnw    = (const float*)d_in[7];
    const float* knw    = (const float*)d_in[8];
    const float* gw     = (const float*)d_in[9];
    const float* lA     = (const float*)d_in[10];
    const float* lB     = (const float*)d_in[11];
    float* out = (float*)d_out;

    // workspace layout (~105.1 MB, lifetime-aliased; r1/r2 proved >=120 MB available):
    //  [0,16M):    hid_bf (dead after QKV gemm)   -> Qb (normrope)
    //  [16M,32M):  wqkv_bf (dead after QKV gemm)  -> Kb [16,24) + Vt [24,32)
    //  [32M,40M):  wo_bf (live to final gemm)
    //  [40M,104M): qkv fp32 (dead after normrope+vtrans) -> attn_bf [40,56)
    //  [104M,+):   Acat 256K | Bt 256K | G 512K | ew 64K   (written at prep time)
    char* ws = (char*)d_ws;
    __hip_bfloat16* hid_bf  = (__hip_bfloat16*)ws;
    __hip_bfloat16* wqkv_bf = (__hip_bfloat16*)(ws + (16u << 20));
    __hip_bfloat16* wo_bf   = (__hip_bfloat16*)(ws + (32u << 20));
    float*          qkv     = (float*)(ws + (40u << 20));
    __hip_bfloat16* attn_bf = (__hip_bfloat16*)(ws + (40u << 20));  // alias qkv (after dead)
    ushort*         Qb      = (ushort*)ws;                          // alias hid_bf
    ushort*         Kb      = (ushort*)(ws + (16u << 20));          // alias wqkv_bf[0:8M)
    ushort*         Vt      = (ushort*)(ws + (24u << 20));          // alias wqkv_bf[8M:16M)
    ushort*         Acat    = (ushort*)(ws + (104u << 20));                 // 256 KB
    ushort*         Bt      = (ushort*)(ws + (104u << 20) + (256u << 10));  // 256 KB
    ushort*         G       = (ushort*)(ws + (104u << 20) + (512u << 10));  // 512 KB
    float*          ew      = (float*)(ws + (105u << 20));                  // 64 KB

    // 1. fused weight casts (Wq/Wk/Wv/Wo/lA)
    wcast_kernel<<<12416, 256, 0, stream>>>(Wq, Wk, Wv, Wo, lA,
                                            wqkv_bf, wo_bf, (__hip_bfloat16*)Acat);
    // 2. fused hidden cast + gate
    gatecast_kernel<<<4096, 256, 0, stream>>>(hidden, gw, hid_bf, ew);
    // 3. LoRA B transpose
    btrans_kernel<<<512, 256, 0, stream>>>(lB, Bt);

    // 4. fused QKV projection (M=4096, N=4096, K=2048) -> fp32 qkv
    //    256x256-tile 8-phase schedule (T2 swizzle + counted vmcnt + setprio)
    gemm256<<<dim3(16, 16), 512, 0, stream>>>((const ushort*)hid_bf, (const ushort*)wqkv_bf,
                                              qkv, NTOK, QKV_CH, DMODEL);

    // 5. RMSNorm + RoPE -> Qb/Kb ; V transpose -> Vt (qkv dead after these)
    normrope_kernel<<<24576, 256, 0, stream>>>(qkv, cosb, sinb, qnw, knw, Qb, Kb);
    vtrans_kernel<<<512, 256, 0, stream>>>(qkv, Vt);

    // 6. flash attention -> attn_bf
    fattn_kernel<<<1024, 256, 0, stream>>>(Qb, Kb, Vt, attn_bf);

    // 7. LoRA H: G = 2*ew*(attn @ Acat^T)  (M=4096, N=64, K=2048)
    lora_h_kernel<<<64, 256, 0, stream>>>((const ushort*)attn_bf, Acat, ew, G);

    // 8. output projection + fused LoRA delta -> d_out
    gemm_bt_lora<<<dim3(16, 32), 256, 0, stream>>>((const ushort*)attn_bf, (const ushort*)wo_bf,
                                                   G, Bt, out);
}

// Round 2
// 379.428 us; speedup vs baseline: 1.0799x; 1.0225x over previous
//
#include <hip/hip_runtime.h>
#include <hip/hip_bf16.h>

// Problem constants
#define S_LEN   1024
#define BATCH   4
#define DMODEL  2048
#define NHEADS  16
#define NKVH    8
#define HEADD   128
#define NTOK    4096      // BATCH*S_LEN
#define QKV_CH  4096      // 2048 q + 1024 k + 1024 v

typedef __bf16 bf16x8 __attribute__((ext_vector_type(8)));
typedef float  f32x4  __attribute__((ext_vector_type(4)));

__device__ __forceinline__ float bf2f(unsigned short u) {
    return __uint_as_float(((unsigned)u) << 16);
}
__device__ __forceinline__ ushort f2bu(float f) {
    union { __hip_bfloat16 h; ushort u; } c;
    c.h = __float2bfloat16(f);
    return c.u;
}
// async global->LDS, 16B per lane; LDS dest must be wave-contiguous in lane order
__device__ __forceinline__ void gl_lds16(const ushort* g, ushort* l) {
    __builtin_amdgcn_global_load_lds(
        (const __attribute__((address_space(1))) void*)g,
        (__attribute__((address_space(3))) void*)l,
        16, 0, 0);
}

// ---------------- fused weight casts: Wq/Wk/Wv/Wo/lA fp32 -> bf16 ----------------
__global__ __launch_bounds__(256) void wcast_kernel(const float* __restrict__ Wq,
                                                    const float* __restrict__ Wk,
                                                    const float* __restrict__ Wv,
                                                    const float* __restrict__ Wo,
                                                    const float* __restrict__ lA,
                                                    __hip_bfloat16* __restrict__ wqkv,
                                                    __hip_bfloat16* __restrict__ wo,
                                                    __hip_bfloat16* __restrict__ acat) {
    int i = blockIdx.x * 256 + threadIdx.x;
    const float* src; __hip_bfloat16* dst; int off;
    if (i < 1048576)      { src = Wq; dst = wqkv;           off = i; }
    else if (i < 1572864) { src = Wk; dst = wqkv + 4194304; off = i - 1048576; }
    else if (i < 2097152) { src = Wv; dst = wqkv + 6291456; off = i - 1572864; }
    else if (i < 3145728) { src = Wo; dst = wo;             off = i - 2097152; }
    else if (i < 3178496) { src = lA; dst = acat;           off = i - 3145728; }
    else return;
    float4 v = ((const float4*)src)[off];
    union { ushort4 u; __hip_bfloat16 h[4]; } r;
    r.h[0] = __float2bfloat16(v.x);
    r.h[1] = __float2bfloat16(v.y);
    r.h[2] = __float2bfloat16(v.z);
    r.h[3] = __float2bfloat16(v.w);
    ((ushort4*)dst)[off] = r.u;
}

// ---------------- lB (e,d,r) fp32 -> Bt[d][e*16+r] bf16 ----------------
__global__ __launch_bounds__(256) void btrans_kernel(const float* __restrict__ lB,
                                                     ushort* __restrict__ Bt) {
    int idx = blockIdx.x * 256 + threadIdx.x;   // 131072
    int d = idx >> 6, er = idx & 63;
    int e = er >> 4, r = er & 15;
    Bt[idx] = f2bu(lB[((size_t)e * DMODEL + d) * 16 + r]);
}

// ---------------- fused hidden cast + gate (block = one token) ----------------
__global__ __launch_bounds__(256) void gatecast_kernel(const float* __restrict__ X,
                                                       const float* __restrict__ GW,
                                                       __hip_bfloat16* __restrict__ Xb,
                                                       float* __restrict__ EW) {
    __shared__ float red[4][257];
    const int t = blockIdx.x, tid = threadIdx.x;
    const float* x = X + (size_t)t * DMODEL;
    __hip_bfloat16* xb = Xb + (size_t)t * DMODEL;
    float p0 = 0.f, p1 = 0.f, p2 = 0.f, p3 = 0.f;
#pragma unroll
    for (int c = 0; c < 2; c++) {
        int i4 = tid + c * 256;           // float4 group in row
        float4 v = ((const float4*)x)[i4];
        union { ushort4 u; __hip_bfloat16 h[4]; } r;
        r.h[0] = __float2bfloat16(v.x);
        r.h[1] = __float2bfloat16(v.y);
        r.h[2] = __float2bfloat16(v.z);
        r.h[3] = __float2bfloat16(v.w);
        ((ushort4*)xb)[i4] = r.u;
        int d = i4 * 4;
        const float* g0 = GW + d;
        p0 += v.x * g0[0] + v.y * g0[1] + v.z * g0[2] + v.w * g0[3];
        const float* g1 = GW + DMODEL + d;
        p1 += v.x * g1[0] + v.y * g1[1] + v.z * g1[2] + v.w * g1[3];
        const float* g2 = GW + 2 * DMODEL + d;
        p2 += v.x * g2[0] + v.y * g2[1] + v.z * g2[2] + v.w * g2[3];
        const float* g3 = GW + 3 * DMODEL + d;
        p3 += v.x * g3[0] + v.y * g3[1] + v.z * g3[2] + v.w * g3[3];
    }
    red[0][tid] = p0; red[1][tid] = p1; red[2][tid] = p2; red[3][tid] = p3;
    __syncthreads();
    for (int s = 128; s > 0; s >>= 1) {
        if (tid < s) {
            red[0][tid] += red[0][tid + s];
            red[1][tid] += red[1][tid + s];
            red[2][tid] += red[2][tid + s];
            red[3][tid] += red[3][tid + s];
        }
        __syncthreads();
    }
    if (tid == 0) {
        float l[4] = { red[0][0], red[1][0], red[2][0], red[3][0] };
        float mx = fmaxf(fmaxf(l[0], l[1]), fmaxf(l[2], l[3]));
        float pe[4], sum = 0.f;
        for (int e = 0; e < 4; e++) { pe[e] = __expf(l[e] - mx); sum += pe[e]; }
        float inv = 1.0f / sum;
        for (int e = 0; e < 4; e++) pe[e] *= inv;
        int i1 = 0;
        for (int e = 1; e < 4; e++) if (pe[e] > pe[i1]) i1 = e;
        int i2 = -1;
        for (int e = 0; e < 4; e++) if (e != i1 && (i2 < 0 || pe[e] > pe[i2])) i2 = e;
        float o[4] = {0.f, 0.f, 0.f, 0.f};
        o[i1] = pe[i1]; o[i2] = pe[i2];
        float* ew = EW + (size_t)t * 4;
        ew[0] = o[0]; ew[1] = o[1]; ew[2] = o[2]; ew[3] = o[3];
    }
}

// =====================================================================================
// 256x256 8-phase bf16 GEMM (T2 swizzle + T3/T4 counted vmcnt + T5 setprio + T1 XCD)
// C[M][N] = A[M][K] * B[N][K]^T, fp32 C. 512 threads = 8 waves (2M x 4N), BK=64.
// LDS 128 KiB: [buf0-A | buf0-B | buf1-A | buf1-B], each 256x64 bf16, XOR-swizzled:
//   element (row,col) lives at ushort offset row*64 + (col ^ ((row&7)<<3)).
// Staged via global_load_lds with linear LDS dest + inverse-swizzled GLOBAL source.
//
// Round-2 fix: fragments are read from LDS ONCE per K-tile and HELD IN REGISTERS
// across quadrant phases (m201 read-count parity: 12/4/8/0 ds_read_b128 per phase,
// was 12/12/12/12 — the lgkmcnt(0) critical path was LDS-read-bound at MfmaUtil 32%).
//   P1: read A0+B0, MFMA Q(0,0)   P2: read B1, MFMA Q(0,1) [A0 held]
//   P3: read A1,    MFMA Q(1,0)   P4: no reads, MFMA Q(1,1) [A1,B1 held]
// Stage schedule / vmcnt counts unchanged from round-1 (WAR/RAW re-verified).
// =====================================================================================
#define LDSA0 0
#define LDSB0 16384
#define LDSA1 32768
#define LDSB1 49152

#define FENCE_BAR() do { asm volatile("" ::: "memory"); __builtin_amdgcn_s_barrier(); } while (0)

__device__ __forceinline__ void stage_half(const ushort* src, ushort* dst, int ld) {
    // half-tile = 128 rows x 64 cols bf16 = 16 KB = 2 x (512 lanes x 16 B)
    gl_lds16(src, dst);
    gl_lds16(src + (size_t)64 * ld, dst + 4096);
}

#define PHASE_MFMA_PRE()  do { \
    asm volatile("" ::: "memory"); \
    __builtin_amdgcn_s_barrier(); \
    asm volatile("s_waitcnt lgkmcnt(0)" ::: "memory"); \
    __builtin_amdgcn_sched_barrier(0); \
    __builtin_amdgcn_s_setprio(1); } while (0)

#define PHASE_MFMA_POST() do { \
    __builtin_amdgcn_s_setprio(0); } while (0)

// one K-tile (BK=64), 4 phases, fragments held in registers across phases
__device__ __forceinline__ void ktile(const ushort* As, const ushort* Bs,
                                      f32x4 (&acc)[8][4],
                                      int aBase, int bBase, int cs0, int cs1,
                                      const ushort* s1s, ushort* s1d, bool s12en,
                                      const ushort* s2s, ushort* s2d,
                                      const ushort* s3s, ushort* s3d, bool s34en,
                                      const ushort* s4s, ushort* s4d,
                                      int K, bool lastVm)
{
    bf16x8 a0[4][2], a1[4][2], b0[2][2], b1[2][2];

    // ---- P1: read A-half0 (8) + B-half0 (4); stage s1; MFMA Q(0,0) ----
#pragma unroll
    for (int ii = 0; ii < 4; ii++) {
        a0[ii][0] = *(const bf16x8*)(As + aBase + ii * 2048 + cs0);
        a0[ii][1] = *(const bf16x8*)(As + aBase + ii * 2048 + cs1);
    }
#pragma unroll
    for (int jj = 0; jj < 2; jj++) {
        b0[jj][0] = *(const bf16x8*)(Bs + bBase + jj * 4096 + cs0);
        b0[jj][1] = *(const bf16x8*)(Bs + bBase + jj * 4096 + cs1);
    }
    if (s12en) stage_half(s1s, s1d, K);
    PHASE_MFMA_PRE();
#pragma unroll
    for (int k = 0; k < 2; k++)
#pragma unroll
        for (int ii = 0; ii < 4; ii++)
#pragma unroll
            for (int jj = 0; jj < 2; jj++)
                acc[ii][2 * jj] = __builtin_amdgcn_mfma_f32_16x16x32_bf16(
                    a0[ii][k], b0[jj][k], acc[ii][2 * jj], 0, 0, 0);
    PHASE_MFMA_POST();
    FENCE_BAR();

    // ---- P2: read B-half1 (4); stage s2; MFMA Q(0,1) with held A0 ----
#pragma unroll
    for (int jj = 0; jj < 2; jj++) {
        b1[jj][0] = *(const bf16x8*)(Bs + bBase + 8192 + jj * 4096 + cs0);
        b1[jj][1] = *(const bf16x8*)(Bs + bBase + 8192 + jj * 4096 + cs1);
    }
    if (s12en) stage_half(s2s, s2d, K);
    PHASE_MFMA_PRE();
#pragma unroll
    for (int k = 0; k < 2; k++)
#pragma unroll
        for (int ii = 0; ii < 4; ii++)
#pragma unroll
            for (int jj = 0; jj < 2; jj++)
                acc[ii][1 + 2 * jj] = __builtin_amdgcn_mfma_f32_16x16x32_bf16(
                    a0[ii][k], b1[jj][k], acc[ii][1 + 2 * jj], 0, 0, 0);
    PHASE_MFMA_POST();
    FENCE_BAR();

    // ---- P3: read A-half1 (8); stage s3; MFMA Q(1,0) with held B0 ----
#pragma unroll
    for (int ii = 0; ii < 4; ii++) {
        a1[ii][0] = *(const bf16x8*)(As + aBase + 8192 + ii * 2048 + cs0);
        a1[ii][1] = *(const bf16x8*)(As + aBase + 8192 + ii * 2048 + cs1);
    }
    if (s34en) stage_half(s3s, s3d, K);
    PHASE_MFMA_PRE();
#pragma unroll
    for (int k = 0; k < 2; k++)
#pragma unroll
        for (int ii = 0; ii < 4; ii++)
#pragma unroll
            for (int jj = 0; jj < 2; jj++)
                acc[4 + ii][2 * jj] = __builtin_amdgcn_mfma_f32_16x16x32_bf16(
                    a1[ii][k], b0[jj][k], acc[4 + ii][2 * jj], 0, 0, 0);
    PHASE_MFMA_POST();
    FENCE_BAR();

    // ---- P4: no reads; stage s4; MFMA Q(1,1) with held A1,B1; counted vmcnt ----
    if (s34en) stage_half(s4s, s4d, K);
    asm volatile("" ::: "memory");
    __builtin_amdgcn_s_barrier();
    __builtin_amdgcn_sched_barrier(0);
    __builtin_amdgcn_s_setprio(1);
#pragma unroll
    for (int k = 0; k < 2; k++)
#pragma unroll
        for (int ii = 0; ii < 4; ii++)
#pragma unroll
            for (int jj = 0; jj < 2; jj++)
                acc[4 + ii][1 + 2 * jj] = __builtin_amdgcn_mfma_f32_16x16x32_bf16(
                    a1[ii][k], b1[jj][k], acc[4 + ii][1 + 2 * jj], 0, 0, 0);
    __builtin_amdgcn_s_setprio(0);
    if (lastVm) { asm volatile("s_waitcnt vmcnt(0)" ::: "memory"); }
    else        { asm volatile("s_waitcnt vmcnt(4)" ::: "memory"); }
    __builtin_amdgcn_s_barrier();
}

__global__ __launch_bounds__(512, 2) void gemm256(const ushort* __restrict__ A,
                                                  const ushort* __restrict__ B,
                                                  float* __restrict__ C,
                                                  int M, int N, int K) {
    __shared__ __align__(16) ushort lds[65536];   // 128 KiB
    const int tid  = threadIdx.x;
    const int wave = tid >> 6, lane = tid & 63;
    const int l16  = lane & 15, quad = lane >> 4;
    const int wm = wave >> 2, wn = wave & 3;

    // T1: XCD-aware chunked swizzle (256 blocks, 256%8==0 -> bijective).
    // Each XCD gets 32 consecutive tile-ids = 2 full block-rows -> A-panel L2 reuse.
    // NOTE: assumes N=4096 (16 block-cols); this kernel is only launched at 4096x4096.
    const int wg0 = blockIdx.x;
    const int swz = (wg0 & 7) * 32 + (wg0 >> 3);
    const int m0 = (swz >> 4) * 256, n0 = (swz & 15) * 256;

    // stage-source constants: thread tid fills LDS ushorts [tid*8, tid*8+8) of a half,
    // i.e. local row tid>>3, swizzled col -> read from inverse-swizzled global col.
    const int srow = tid >> 3;
    const int scol = ((tid & 7) * 8) ^ ((srow & 7) << 3);
    const ushort* aSrc = A + (size_t)(m0 + srow) * K + scol;
    const ushort* bSrc = B + (size_t)(n0 + srow) * K + scol;

    // ds_read constants: row = (frag base)+l16; swizzled col = ((k*4+quad)^(l16&7))*8
    const int aBase = (wm * 16 + l16) * 64;
    const int bBase = (wn * 16 + l16) * 64;
    const int cs0 = ((0 + quad) ^ (l16 & 7)) * 8;
    const int cs1 = ((4 + quad) ^ (l16 & 7)) * 8;

    f32x4 acc[8][4];
#pragma unroll
    for (int i = 0; i < 8; i++)
#pragma unroll
        for (int j = 0; j < 4; j++) acc[i][j] = (f32x4){0.f, 0.f, 0.f, 0.f};

    const int NT = K >> 6;   // K-tiles of 64

    const ushort* A0s = lds + LDSA0;
    const ushort* B0s = lds + LDSB0;
    const ushort* A1s = lds + LDSA1;
    const ushort* B1s = lds + LDSB1;

    // prologue: tile0 fully -> buf0 (8 loads), tile1 halves A0,B0 -> buf1 (4 loads)
    stage_half(aSrc,                     lds + LDSA0 + tid * 8, K);
    stage_half(aSrc + (size_t)128 * K,   lds + LDSA0 + 8192 + tid * 8, K);
    stage_half(bSrc,                     lds + LDSB0 + tid * 8, K);
    stage_half(bSrc + (size_t)128 * K,   lds + LDSB0 + 8192 + tid * 8, K);
    stage_half(aSrc + 64,                lds + LDSA1 + tid * 8, K);
    stage_half(bSrc + 64,                lds + LDSB1 + tid * 8, K);
    asm volatile("s_waitcnt vmcnt(4)" ::: "memory");   // tile0 resident; tile1 h0 in flight
    __builtin_amdgcn_s_barrier();

    for (int t = 0; t + 1 < NT; t += 2) {
        const bool s34 = (t + 2) < NT, s78 = (t + 3) < NT;
        const int k1 = (t + 1) * 64, k2 = (t + 2) * 64, k3 = (t + 3) * 64;

        // K-tile t (reads buf0):
        //  s1: A-h1(t+1)->buf1   s2: B-h1(t+1)->buf1
        //  s3: A-h0(t+2)->buf0   s4: B-h0(t+2)->buf0
        //  end vmcnt(4): drains prev s3/s4 + s1/s2 -> buf1 complete; s3/s4 in flight
        ktile(A0s, B0s, acc, aBase, bBase, cs0, cs1,
              aSrc + (size_t)128 * K + k1, lds + LDSA1 + 8192 + tid * 8, true,
              bSrc + (size_t)128 * K + k1, lds + LDSB1 + 8192 + tid * 8,
              aSrc + k2,                   lds + LDSA0 + tid * 8, s34,
              bSrc + k2,                   lds + LDSB0 + tid * 8,
              K, !s34);

        // K-tile t+1 (reads buf1):
        //  s1: A-h1(t+2)->buf0   s2: B-h1(t+2)->buf0
        //  s3: A-h0(t+3)->buf1   s4: B-h0(t+3)->buf1
        //  end vmcnt(4): drains s3/s4(tile t) + s1/s2 -> buf0 complete for next iter
        ktile(A1s, B1s, acc, aBase, bBase, cs0, cs1,
              aSrc + (size_t)128 * K + k2, lds + LDSA0 + 8192 + tid * 8, s34,
              bSrc + (size_t)128 * K + k2, lds + LDSB0 + 8192 + tid * 8,
              aSrc + k3,                   lds + LDSA1 + tid * 8, s78,
              bSrc + k3,                   lds + LDSB1 + tid * 8,
              K, !s78);
    }
    // NT even here (K=2048 -> 32 tiles): no tail tile.

    // epilogue: C[m0 + (i&3)*32 + wm*16 + (i>>2)*128 + quad*4 + r]
    //            [n0 + (j&1)*128 + (j>>1)*64 + wn*16 + l16]
    float* crow = C + (size_t)(m0 + wm * 16 + quad * 4) * N + n0 + wn * 16 + l16;
#pragma unroll
    for (int i = 0; i < 8; i++) {
        float* cpi = crow + (size_t)((i & 3) * 32 + (i >> 2) * 128) * N;
#pragma unroll
        for (int r = 0; r < 4; r++)
#pragma unroll
            for (int j = 0; j < 4; j++)
                cpi[(size_t)r * N + ((j & 1) * 128 + (j >> 1) * 64)] = acc[i][j][r];
    }
}

// ---------------- Wo GEMM with fused LoRA delta: C = A*B^T + A2*B2^T (fp32 out) ----------------
__global__ __launch_bounds__(256) void gemm_bt_lora(const ushort* __restrict__ A,
                                                    const ushort* __restrict__ B,
                                                    const ushort* __restrict__ A2,
                                                    const ushort* __restrict__ B2,
                                                    float* __restrict__ C) {
    __shared__ ushort As[128 * 32];
    __shared__ ushort Bs[128 * 32];
    const int tid  = threadIdx.x;
    const int wave = tid >> 6, lane = tid & 63;
    const int l16  = lane & 15, quad = lane >> 4;
    const int m0 = blockIdx.y * 128, n0 = blockIdx.x * 128;
    const int wm = (wave >> 1) * 64, wn = (wave & 1) * 64;
    const int K = DMODEL, N = DMODEL;

    f32x4 acc[4][4];
#pragma unroll
    for (int i = 0; i < 4; i++)
#pragma unroll
        for (int j = 0; j < 4; j++) acc[i][j] = (f32x4){0.f, 0.f, 0.f, 0.f};

    const int r1 = tid >> 2, kg1 = (tid & 3) * 8;
    const int r2 = (tid + 256) >> 2, kg2 = ((tid + 256) & 3) * 8;

    for (int k0 = 0; k0 < K; k0 += 32) {
        __syncthreads();
        gl_lds16(A + (size_t)(m0 + r1) * K + k0 + kg1, As + tid * 8);
        gl_lds16(B + (size_t)(n0 + r1) * K + k0 + kg1, Bs + tid * 8);
        gl_lds16(A + (size_t)(m0 + r2) * K + k0 + kg2, As + (tid + 256) * 8);
        gl_lds16(B + (size_t)(n0 + r2) * K + k0 + kg2, Bs + (tid + 256) * 8);
        __syncthreads();
        bf16x8 af[4], bfr[4];
#pragma unroll
        for (int i = 0; i < 4; i++) {
            af[i]  = *(const bf16x8*)(As + (wm + i * 16 + l16) * 32 + quad * 8);
            bfr[i] = *(const bf16x8*)(Bs + (wn + i * 16 + l16) * 32 + quad * 8);
        }
#pragma unroll
        for (int i = 0; i < 4; i++)
#pragma unroll
            for (int j = 0; j < 4; j++)
                acc[i][j] = __builtin_amdgcn_mfma_f32_16x16x32_bf16(af[i], bfr[j], acc[i][j], 0, 0, 0);
    }

    // LoRA delta: 2 extra K-steps over K2=64
#pragma unroll
    for (int k0 = 0; k0 < 64; k0 += 32) {
        __syncthreads();
        gl_lds16(A2 + (size_t)(m0 + r1) * 64 + k0 + kg1, As + tid * 8);
        gl_lds16(B2 + (size_t)(n0 + r1) * 64 + k0 + kg1, Bs + tid * 8);
        gl_lds16(A2 + (size_t)(m0 + r2) * 64 + k0 + kg2, As + (tid + 256) * 8);
        gl_lds16(B2 + (size_t)(n0 + r2) * 64 + k0 + kg2, Bs + (tid + 256) * 8);
        __syncthreads();
        bf16x8 af[4], bfr[4];
#pragma unroll
        for (int i = 0; i < 4; i++) {
            af[i]  = *(const bf16x8*)(As + (wm + i * 16 + l16) * 32 + quad * 8);
            bfr[i] = *(const bf16x8*)(Bs + (wn + i * 16 + l16) * 32 + quad * 8);
        }
#pragma unroll
        for (int i = 0; i < 4; i++)
#pragma unroll
            for (int j = 0; j < 4; j++)
                acc[i][j] = __builtin_amdgcn_mfma_f32_16x16x32_bf16(af[i], bfr[j], acc[i][j], 0, 0, 0);
    }

#pragma unroll
    for (int i = 0; i < 4; i++)
#pragma unroll
        for (int j = 0; j < 4; j++)
#pragma unroll
            for (int r = 0; r < 4; r++) {
                int m = m0 + wm + i * 16 + quad * 4 + r;
                int n = n0 + wn + j * 16 + l16;
                C[(size_t)m * N + n] = acc[i][j][r];
            }
}

// ---------------- LoRA H: G[t][e*16+r] = bf16(2*ew[t][e] * (x_t . A[e][r])) ----------------
__global__ __launch_bounds__(256) void lora_h_kernel(const ushort* __restrict__ X,
                                                     const ushort* __restrict__ Acat,
                                                     const float* __restrict__ EW,
                                                     ushort* __restrict__ G) {
    __shared__ ushort As[64 * 32];
    __shared__ ushort Bs[64 * 32];
    const int tid = threadIdx.x;
    const int wave = tid >> 6, lane = tid & 63;
    const int l16 = lane & 15, quad = lane >> 4;
    const int m0 = blockIdx.x * 64;

    f32x4 acc[4];
#pragma unroll
    for (int nt = 0; nt < 4; nt++) acc[nt] = (f32x4){0.f, 0.f, 0.f, 0.f};

    const int r1 = tid >> 2, kg1 = (tid & 3) * 8;

    for (int k0 = 0; k0 < DMODEL; k0 += 32) {
        __syncthreads();
        gl_lds16(X + (size_t)(m0 + r1) * DMODEL + k0 + kg1, As + tid * 8);
        gl_lds16(Acat + (size_t)r1 * DMODEL + k0 + kg1, Bs + tid * 8);
        __syncthreads();
        bf16x8 af = *(const bf16x8*)(As + (wave * 16 + l16) * 32 + quad * 8);
#pragma unroll
        for (int nt = 0; nt < 4; nt++) {
            bf16x8 bfr = *(const bf16x8*)(Bs + (nt * 16 + l16) * 32 + quad * 8);
            acc[nt] = __builtin_amdgcn_mfma_f32_16x16x32_bf16(af, bfr, acc[nt], 0, 0, 0);
        }
    }
#pragma unroll
    for (int nt = 0; nt < 4; nt++)
#pragma unroll
        for (int r = 0; r < 4; r++) {
            int m = m0 + wave * 16 + quad * 4 + r;
            float wsc = 2.0f * EW[(size_t)m * 4 + nt];   // LORA_SCALE=2 folded
            G[(size_t)m * 64 + nt * 16 + l16] = f2bu(acc[nt][r] * wsc);
        }
}

// ---------------- RMSNorm + RoPE: fp32 qkv -> bf16 Qb[b,h,s,d] (scaled), Kb[b,kv,s,d] ----------------
__global__ __launch_bounds__(256) void normrope_kernel(const float* __restrict__ QKV,
                                                       const float* __restrict__ cosb,
                                                       const float* __restrict__ sinb,
                                                       const float* __restrict__ qw,
                                                       const float* __restrict__ kw,
                                                       ushort* __restrict__ Qb,
                                                       ushort* __restrict__ Kb) {
    const int wave = threadIdx.x >> 6, lane = threadIdx.x & 63;
    const int r = blockIdx.x * 4 + wave;
    const float* p; const float* w; int t; ushort* dst; float scale;
    if (r < NTOK * NHEADS) {
        t = r >> 4;
        int h = r & 15;
        p = QKV + (size_t)t * QKV_CH + h * HEADD;
        w = qw; scale = 0.08838834764831845f;   // 128^-0.5 folded into Q
        int b = t >> 10, s = t & 1023;
        dst = Qb + ((size_t)((b * 16 + h) * 1024 + s)) * HEADD;
    } else {
        int r2 = r - NTOK * NHEADS;
        t = r2 >> 3;
        int kv = r2 & 7;
        p = QKV + (size_t)t * QKV_CH + 2048 + kv * HEADD;
        w = kw; scale = 1.0f;
        int b = t >> 10, s = t & 1023;
        dst = Kb + ((size_t)((b * 8 + kv) * 1024 + s)) * HEADD;
    }
    float xl = p[lane], xh = p[lane + 64];
    float ss = xl * xl + xh * xh;
#pragma unroll
    for (int mask = 1; mask < 64; mask <<= 1) ss += __shfl_xor(ss, mask);
    float rstd = rsqrtf(ss * (1.0f / 128.0f) + 1e-6f);
    float nl = xl * rstd * w[lane];
    float nh = xh * rstd * w[lane + 64];
    const float* cp = cosb + (size_t)t * HEADD;
    const float* sp = sinb + (size_t)t * HEADD;
    float ol = nl * cp[lane]      - nh * sp[lane];
    float oh = nh * cp[lane + 64] + nl * sp[lane + 64];
    dst[lane]      = f2bu(ol * scale);
    dst[lane + 64] = f2bu(oh * scale);
}

// ---------------- V transpose: fp32 qkv v -> bf16 Vt[b,kv,d,s] ----------------
__global__ __launch_bounds__(256) void vtrans_kernel(const float* __restrict__ QKV,
                                                     ushort* __restrict__ Vt) {
    __shared__ float Ts[64][129];
    const int blk = blockIdx.x;          // 4*8*16
    const int sc = blk & 15;
    const int kvb = blk >> 4;            // b*8+kv
    const int s0 = sc * 64;
    const float* src = QKV + ((size_t)((kvb >> 3) * 1024 + s0)) * QKV_CH + 3072 + (kvb & 7) * HEADD;
    for (int c = threadIdx.x; c < 2048; c += 256) {
        int s = c >> 5, d0 = (c & 31) * 4;
        float4 v = *(const float4*)(src + (size_t)s * QKV_CH + d0);
        Ts[s][d0] = v.x; Ts[s][d0 + 1] = v.y; Ts[s][d0 + 2] = v.z; Ts[s][d0 + 3] = v.w;
    }
    __syncthreads();
    ushort* dst = Vt + ((size_t)kvb * HEADD) * S_LEN + s0;
    for (int c = threadIdx.x; c < 1024; c += 256) {
        int d = c >> 3, s8 = (c & 7) * 8;
        union { ushort u[8]; uint4 v; } pk;
#pragma unroll
        for (int j = 0; j < 8; j++) pk.u[j] = f2bu(Ts[s8 + j][d]);
        *(uint4*)(dst + (size_t)d * S_LEN + s8) = pk.v;
    }
}

// ---------------- flash attention (bf16 MFMA, no-max softmax — exact by boundedness) ----------------
// |q|=|k|=sqrt(128) after rmsnorm, scale 1/sqrt(128) => |s|<=11.4, exp(s)<=9e4: fp32/bf16 safe.
#define KPITCH 136
#define VPITCH 72
__global__ __launch_bounds__(256) void fattn_kernel(const ushort* __restrict__ Qb,
                                                    const ushort* __restrict__ Kb,
                                                    const ushort* __restrict__ Vt,
                                                    __hip_bfloat16* __restrict__ O) {
    __shared__ __align__(16) ushort Ks[64 * KPITCH];
    __shared__ __align__(16) ushort Vs[128 * VPITCH];
    __shared__ __align__(16) ushort Ps[4 * 16 * VPITCH];
    const int tid = threadIdx.x;
    const int wq = tid >> 6, lane = tid & 63;
    const int l16 = lane & 15, quad = lane >> 4;
    const int qblk = 15 - (blockIdx.x >> 6);    // heavy q-blocks first
    const int bh = blockIdx.x & 63;
    const int b = bh >> 4, h = bh & 15;
    const int kvb = b * 8 + (h >> 1);
    const int q0 = qblk * 64;
    const int qbase = q0 + wq * 16;

    bf16x8 qf[4];
    const ushort* qrow = Qb + ((size_t)bh * S_LEN + qbase + l16) * HEADD;
#pragma unroll
    for (int kt = 0; kt < 4; kt++)
        qf[kt] = *(const bf16x8*)(qrow + kt * 32 + quad * 8);

    f32x4 oacc[8];
#pragma unroll
    for (int dt = 0; dt < 8; dt++) oacc[dt] = (f32x4){0.f, 0.f, 0.f, 0.f};
    float l[4] = { 0.f, 0.f, 0.f, 0.f };   // per-lane partial denominators

    const ushort* kbase = Kb + (size_t)kvb * S_LEN * HEADD;
    const ushort* vbase = Vt + (size_t)kvb * HEADD * S_LEN;
    const int ntiles = qblk + 1;

    for (int kb = 0; kb < ntiles; kb++) {
        const int k0 = kb * 64;
        __syncthreads();
        for (int c = tid; c < 1024; c += 256) {
            int row = c >> 4, col = (c & 15) * 8;
            *(uint4*)(Ks + row * KPITCH + col) =
                *(const uint4*)(kbase + (size_t)(k0 + row) * HEADD + col);
        }
        for (int c = tid; c < 1024; c += 256) {
            int row = c >> 3, col = (c & 7) * 8;
            *(uint4*)(Vs + row * VPITCH + col) =
                *(const uint4*)(vbase + (size_t)row * S_LEN + k0 + col);
        }
        __syncthreads();

        f32x4 sacc[4];
#pragma unroll
        for (int nt = 0; nt < 4; nt++) sacc[nt] = (f32x4){0.f, 0.f, 0.f, 0.f};
#pragma unroll
        for (int kt = 0; kt < 4; kt++) {
#pragma unroll
            for (int nt = 0; nt < 4; nt++) {
                bf16x8 kf = *(const bf16x8*)(Ks + (nt * 16 + l16) * KPITCH + kt * 32 + quad * 8);
                sacc[nt] = __builtin_amdgcn_mfma_f32_16x16x32_bf16(qf[kt], kf, sacc[nt], 0, 0, 0);
            }
        }

        // p = exp(s) (no max subtraction), causal mask, accumulate partial l
#pragma unroll
        for (int r = 0; r < 4; r++) {
            const int qg = qbase + quad * 4 + r;
#pragma unroll
            for (int nt = 0; nt < 4; nt++) {
                int kg = k0 + nt * 16 + l16;
                float p = (kg <= qg) ? __expf(sacc[nt][r]) : 0.f;
                l[r] += p;
                Ps[wq * 16 * VPITCH + (quad * 4 + r) * VPITCH + nt * 16 + l16] = f2bu(p);
            }
        }

        // O += P V (unnormalized, no rescale needed)
#pragma unroll
        for (int kt2 = 0; kt2 < 2; kt2++) {
            bf16x8 pf = *(const bf16x8*)(Ps + wq * 16 * VPITCH + l16 * VPITCH + kt2 * 32 + quad * 8);
#pragma unroll
            for (int dt = 0; dt < 8; dt++) {
                bf16x8 vf = *(const bf16x8*)(Vs + (dt * 16 + l16) * VPITCH + kt2 * 32 + quad * 8);
                oacc[dt] = __builtin_amdgcn_mfma_f32_16x16x32_bf16(pf, vf, oacc[dt], 0, 0, 0);
            }
        }
    }

    // epilogue: reduce l across the 16-lane key groups, normalize, store
#pragma unroll
    for (int r = 0; r < 4; r++) {
        float lr = l[r];
        lr += __shfl_xor(lr, 1);
        lr += __shfl_xor(lr, 2);
        lr += __shfl_xor(lr, 4);
        lr += __shfl_xor(lr, 8);
        float inv = 1.0f / lr;
        size_t base = ((size_t)(b * S_LEN + qbase + quad * 4 + r)) * (NHEADS * HEADD) + h * HEADD;
#pragma unroll
        for (int dt = 0; dt < 8; dt++)
            O[base + dt * 16 + l16] = __float2bfloat16(oacc[dt][r] * inv);
    }
}

extern "C" void kernel_launch(void* const* d_in, const int* in_sizes, int n_in,
                              void* d_out, int out_size, void* d_ws, size_t ws_size,
                              hipStream_t stream) {
    const float* hidden = (const float*)d_in[0];
    const float* cosb   = (const float*)d_in[1];
    const float* sinb   = (const float*)d_in[2];
    const float* Wq     = (const float*)d_in[3];
    const float* Wk     = (const float*)d_in[4];
    const float* Wv     = (const float*)d_in[5];
    const float* Wo     = (const float*)d_in[6];
    const float* qnw    = (const float*)d_in[7];
    const float* knw    = (const float*)d_in[8];
    const float* gw     = (const float*)d_in[9];
    const float* lA     = (const float*)d_in[10];
    const float* lB     = (const float*)d_in[11];
    float* out = (float*)d_out;

    // workspace layout (~105.1 MB, lifetime-aliased; r1/r2 proved >=120 MB available):
    //  [0,16M):    hid_bf (dead after QKV gemm)   -> Qb (normrope)
    //  [16M,32M):  wqkv_bf (dead after QKV gemm)  -> Kb [16,24) + Vt [24,32)
    //  [32M,40M):  wo_bf (live to final gemm)
    //  [40M,104M): qkv fp32 (dead after normrope+vtrans) -> attn_bf [40,56)
    //  [104M,+):   Acat 256K | Bt 256K | G 512K | ew 64K   (written at prep time)
    char* ws = (char*)d_ws;
    __hip_bfloat16* hid_bf  = (__hip_bfloat16*)ws;
    __hip_bfloat16* wqkv_bf = (__hip_bfloat16*)(ws + (16u << 20));
    __hip_bfloat16* wo_bf   = (__hip_bfloat16*)(ws + (32u << 20));
    float*          qkv     = (float*)(ws + (40u << 20));
    __hip_bfloat16* attn_bf = (__hip_bfloat16*)(ws + (40u << 20));  // alias qkv (after dead)
    ushort*         Qb      = (ushort*)ws;                          // alias hid_bf
    ushort*         Kb      = (ushort*)(ws + (16u << 20));          // alias wqkv_bf[0:8M)
    ushort*         Vt      = (ushort*)(ws + (24u << 20));          // alias wqkv_bf[8M:16M)
    ushort*         Acat    = (ushort*)(ws + (104u << 20));                 // 256 KB
    ushort*         Bt      = (ushort*)(ws + (104u << 20) + (256u << 10));  // 256 KB
    ushort*         G       = (ushort*)(ws + (104u << 20) + (512u << 10));  // 512 KB
    float*          ew      = (float*)(ws + (105u << 20));                  // 64 KB

    // 1. fused weight casts (Wq/Wk/Wv/Wo/lA)
    wcast_kernel<<<12416, 256, 0, stream>>>(Wq, Wk, Wv, Wo, lA,
                                            wqkv_bf, wo_bf, (__hip_bfloat16*)Acat);
    // 2. fused hidden cast + gate
    gatecast_kernel<<<4096, 256, 0, stream>>>(hidden, gw, hid_bf, ew);
    // 3. LoRA B transpose
    btrans_kernel<<<512, 256, 0, stream>>>(lB, Bt);

    // 4. fused QKV projection (M=4096, N=4096, K=2048) -> fp32 qkv
    //    256x256-tile 8-phase schedule, frag-reuse (12/4/8/0 reads), XCD swizzle
    gemm256<<<256, 512, 0, stream>>>((const ushort*)hid_bf, (const ushort*)wqkv_bf,
                                     qkv, NTOK, QKV_CH, DMODEL);

    // 5. RMSNorm + RoPE -> Qb/Kb ; V transpose -> Vt (qkv dead after these)
    normrope_kernel<<<24576, 256, 0, stream>>>(qkv, cosb, sinb, qnw, knw, Qb, Kb);
    vtrans_kernel<<<512, 256, 0, stream>>>(qkv, Vt);

    // 6. flash attention -> attn_bf
    fattn_kernel<<<1024, 256, 0, stream>>>(Qb, Kb, Vt, attn_bf);

    // 7. LoRA H: G = 2*ew*(attn @ Acat^T)  (M=4096, N=64, K=2048)
    lora_h_kernel<<<64, 256, 0, stream>>>((const ushort*)attn_bf, Acat, ew, G);

    // 8. output projection + fused LoRA delta -> d_out
    gemm_bt_lora<<<dim3(16, 32), 256, 0, stream>>>((const ushort*)attn_bf, (const ushort*)wo_bf,
                                                   G, Bt, out);
}

// Round 3
// 374.498 us; speedup vs baseline: 1.0941x; 1.0132x over previous
//
#include <hip/hip_runtime.h>
#include <hip/hip_bf16.h>

// Problem constants
#define S_LEN   1024
#define BATCH   4
#define DMODEL  2048
#define NHEADS  16
#define NKVH    8
#define HEADD   128
#define NTOK    4096      // BATCH*S_LEN
#define QKV_CH  4096      // 2048 q + 1024 k + 1024 v

typedef __bf16 bf16x8 __attribute__((ext_vector_type(8)));
typedef float  f32x4  __attribute__((ext_vector_type(4)));

__device__ __forceinline__ float bf2f(unsigned short u) {
    return __uint_as_float(((unsigned)u) << 16);
}
__device__ __forceinline__ ushort f2bu(float f) {
    union { __hip_bfloat16 h; ushort u; } c;
    c.h = __float2bfloat16(f);
    return c.u;
}
// async global->LDS, 16B per lane; LDS dest must be wave-contiguous in lane order
__device__ __forceinline__ void gl_lds16(const ushort* g, ushort* l) {
    __builtin_amdgcn_global_load_lds(
        (const __attribute__((address_space(1))) void*)g,
        (__attribute__((address_space(3))) void*)l,
        16, 0, 0);
}

// ---------------- fused weight casts: Wq/Wk/Wv/Wo/lA fp32 -> bf16 ----------------
__global__ __launch_bounds__(256) void wcast_kernel(const float* __restrict__ Wq,
                                                    const float* __restrict__ Wk,
                                                    const float* __restrict__ Wv,
                                                    const float* __restrict__ Wo,
                                                    const float* __restrict__ lA,
                                                    __hip_bfloat16* __restrict__ wqkv,
                                                    __hip_bfloat16* __restrict__ wo,
                                                    __hip_bfloat16* __restrict__ acat) {
    int i = blockIdx.x * 256 + threadIdx.x;
    const float* src; __hip_bfloat16* dst; int off;
    if (i < 1048576)      { src = Wq; dst = wqkv;           off = i; }
    else if (i < 1572864) { src = Wk; dst = wqkv + 4194304; off = i - 1048576; }
    else if (i < 2097152) { src = Wv; dst = wqkv + 6291456; off = i - 1572864; }
    else if (i < 3145728) { src = Wo; dst = wo;             off = i - 2097152; }
    else if (i < 3178496) { src = lA; dst = acat;           off = i - 3145728; }
    else return;
    float4 v = ((const float4*)src)[off];
    union { ushort4 u; __hip_bfloat16 h[4]; } r;
    r.h[0] = __float2bfloat16(v.x);
    r.h[1] = __float2bfloat16(v.y);
    r.h[2] = __float2bfloat16(v.z);
    r.h[3] = __float2bfloat16(v.w);
    ((ushort4*)dst)[off] = r.u;
}

// ---------------- lB (e,d,r) fp32 -> Bt[d][e*16+r] bf16 ----------------
__global__ __launch_bounds__(256) void btrans_kernel(const float* __restrict__ lB,
                                                     ushort* __restrict__ Bt) {
    int idx = blockIdx.x * 256 + threadIdx.x;   // 131072
    int d = idx >> 6, er = idx & 63;
    int e = er >> 4, r = er & 15;
    Bt[idx] = f2bu(lB[((size_t)e * DMODEL + d) * 16 + r]);
}

// ---------------- fused hidden cast + gate (block = one token) ----------------
__global__ __launch_bounds__(256) void gatecast_kernel(const float* __restrict__ X,
                                                       const float* __restrict__ GW,
                                                       __hip_bfloat16* __restrict__ Xb,
                                                       float* __restrict__ EW) {
    __shared__ float red[4][257];
    const int t = blockIdx.x, tid = threadIdx.x;
    const float* x = X + (size_t)t * DMODEL;
    __hip_bfloat16* xb = Xb + (size_t)t * DMODEL;
    float p0 = 0.f, p1 = 0.f, p2 = 0.f, p3 = 0.f;
#pragma unroll
    for (int c = 0; c < 2; c++) {
        int i4 = tid + c * 256;           // float4 group in row
        float4 v = ((const float4*)x)[i4];
        union { ushort4 u; __hip_bfloat16 h[4]; } r;
        r.h[0] = __float2bfloat16(v.x);
        r.h[1] = __float2bfloat16(v.y);
        r.h[2] = __float2bfloat16(v.z);
        r.h[3] = __float2bfloat16(v.w);
        ((ushort4*)xb)[i4] = r.u;
        int d = i4 * 4;
        const float* g0 = GW + d;
        p0 += v.x * g0[0] + v.y * g0[1] + v.z * g0[2] + v.w * g0[3];
        const float* g1 = GW + DMODEL + d;
        p1 += v.x * g1[0] + v.y * g1[1] + v.z * g1[2] + v.w * g1[3];
        const float* g2 = GW + 2 * DMODEL + d;
        p2 += v.x * g2[0] + v.y * g2[1] + v.z * g2[2] + v.w * g2[3];
        const float* g3 = GW + 3 * DMODEL + d;
        p3 += v.x * g3[0] + v.y * g3[1] + v.z * g3[2] + v.w * g3[3];
    }
    red[0][tid] = p0; red[1][tid] = p1; red[2][tid] = p2; red[3][tid] = p3;
    __syncthreads();
    for (int s = 128; s > 0; s >>= 1) {
        if (tid < s) {
            red[0][tid] += red[0][tid + s];
            red[1][tid] += red[1][tid + s];
            red[2][tid] += red[2][tid + s];
            red[3][tid] += red[3][tid + s];
        }
        __syncthreads();
    }
    if (tid == 0) {
        float l[4] = { red[0][0], red[1][0], red[2][0], red[3][0] };
        float mx = fmaxf(fmaxf(l[0], l[1]), fmaxf(l[2], l[3]));
        float pe[4], sum = 0.f;
        for (int e = 0; e < 4; e++) { pe[e] = __expf(l[e] - mx); sum += pe[e]; }
        float inv = 1.0f / sum;
        for (int e = 0; e < 4; e++) pe[e] *= inv;
        int i1 = 0;
        for (int e = 1; e < 4; e++) if (pe[e] > pe[i1]) i1 = e;
        int i2 = -1;
        for (int e = 0; e < 4; e++) if (e != i1 && (i2 < 0 || pe[e] > pe[i2])) i2 = e;
        float o[4] = {0.f, 0.f, 0.f, 0.f};
        o[i1] = pe[i1]; o[i2] = pe[i2];
        float* ew = EW + (size_t)t * 4;
        ew[0] = o[0]; ew[1] = o[1]; ew[2] = o[2]; ew[3] = o[3];
    }
}

// =====================================================================================
// 256x256 8-phase bf16 GEMM with FUSED RMSNorm+RoPE+V-transpose epilogue.
// A[M][K] * B[N][K]^T -> writes Qb (norm+rope+scale), Kb (norm+rope), Vt (transposed)
// directly in bf16; the fp32 qkv intermediate (64 MB write + 66 MB re-read) is gone.
// Main loop = round-2 proven schedule (frag-reuse 12/4/8/0 reads, counted vmcnt(4),
// T2 swizzle, T5 setprio, T1 XCD swizzle) + template's lgkmcnt(8) hint in P1.
// Tile = 256 tokens x 256 qkv-channels = always 2 complete heads; fragment layout
// pairs d and d+64 of a head in the SAME thread -> RoPE rotate-half is register-local.
// =====================================================================================
#define LDSA0 0
#define LDSB0 16384
#define LDSA1 32768
#define LDSB1 49152

#define FENCE_BAR() do { asm volatile("" ::: "memory"); __builtin_amdgcn_s_barrier(); } while (0)

__device__ __forceinline__ void stage_half(const ushort* src, ushort* dst, int ld) {
    // half-tile = 128 rows x 64 cols bf16 = 16 KB = 2 x (512 lanes x 16 B)
    gl_lds16(src, dst);
    gl_lds16(src + (size_t)64 * ld, dst + 4096);
}

#define PHASE_MFMA_PRE()  do { \
    asm volatile("" ::: "memory"); \
    __builtin_amdgcn_s_barrier(); \
    asm volatile("s_waitcnt lgkmcnt(0)" ::: "memory"); \
    __builtin_amdgcn_sched_barrier(0); \
    __builtin_amdgcn_s_setprio(1); } while (0)

#define PHASE_MFMA_POST() do { \
    __builtin_amdgcn_s_setprio(0); } while (0)

// one K-tile (BK=64), 4 phases, fragments held in registers across phases
__device__ __forceinline__ void ktile(const ushort* As, const ushort* Bs,
                                      f32x4 (&acc)[8][4],
                                      int aBase, int bBase, int cs0, int cs1,
                                      const ushort* s1s, ushort* s1d, bool s12en,
                                      const ushort* s2s, ushort* s2d,
                                      const ushort* s3s, ushort* s3d, bool s34en,
                                      const ushort* s4s, ushort* s4d,
                                      int K, bool lastVm)
{
    bf16x8 a0[4][2], a1[4][2], b0[2][2], b1[2][2];

    // ---- P1: read A-half0 (8) + B-half0 (4); stage s1; MFMA Q(0,0) ----
#pragma unroll
    for (int ii = 0; ii < 4; ii++) {
        a0[ii][0] = *(const bf16x8*)(As + aBase + ii * 2048 + cs0);
        a0[ii][1] = *(const bf16x8*)(As + aBase + ii * 2048 + cs1);
    }
#pragma unroll
    for (int jj = 0; jj < 2; jj++) {
        b0[jj][0] = *(const bf16x8*)(Bs + bBase + jj * 4096 + cs0);
        b0[jj][1] = *(const bf16x8*)(Bs + bBase + jj * 4096 + cs1);
    }
    if (s12en) stage_half(s1s, s1d, K);
    asm volatile("s_waitcnt lgkmcnt(8)" ::: "memory");   // early-drain hint (12-read phase)
    PHASE_MFMA_PRE();
#pragma unroll
    for (int k = 0; k < 2; k++)
#pragma unroll
        for (int ii = 0; ii < 4; ii++)
#pragma unroll
            for (int jj = 0; jj < 2; jj++)
                acc[ii][2 * jj] = __builtin_amdgcn_mfma_f32_16x16x32_bf16(
                    a0[ii][k], b0[jj][k], acc[ii][2 * jj], 0, 0, 0);
    PHASE_MFMA_POST();
    FENCE_BAR();

    // ---- P2: read B-half1 (4); stage s2; MFMA Q(0,1) with held A0 ----
#pragma unroll
    for (int jj = 0; jj < 2; jj++) {
        b1[jj][0] = *(const bf16x8*)(Bs + bBase + 8192 + jj * 4096 + cs0);
        b1[jj][1] = *(const bf16x8*)(Bs + bBase + 8192 + jj * 4096 + cs1);
    }
    if (s12en) stage_half(s2s, s2d, K);
    PHASE_MFMA_PRE();
#pragma unroll
    for (int k = 0; k < 2; k++)
#pragma unroll
        for (int ii = 0; ii < 4; ii++)
#pragma unroll
            for (int jj = 0; jj < 2; jj++)
                acc[ii][1 + 2 * jj] = __builtin_amdgcn_mfma_f32_16x16x32_bf16(
                    a0[ii][k], b1[jj][k], acc[ii][1 + 2 * jj], 0, 0, 0);
    PHASE_MFMA_POST();
    FENCE_BAR();

    // ---- P3: read A-half1 (8); stage s3; MFMA Q(1,0) with held B0 ----
#pragma unroll
    for (int ii = 0; ii < 4; ii++) {
        a1[ii][0] = *(const bf16x8*)(As + aBase + 8192 + ii * 2048 + cs0);
        a1[ii][1] = *(const bf16x8*)(As + aBase + 8192 + ii * 2048 + cs1);
    }
    if (s34en) stage_half(s3s, s3d, K);
    PHASE_MFMA_PRE();
#pragma unroll
    for (int k = 0; k < 2; k++)
#pragma unroll
        for (int ii = 0; ii < 4; ii++)
#pragma unroll
            for (int jj = 0; jj < 2; jj++)
                acc[4 + ii][2 * jj] = __builtin_amdgcn_mfma_f32_16x16x32_bf16(
                    a1[ii][k], b0[jj][k], acc[4 + ii][2 * jj], 0, 0, 0);
    PHASE_MFMA_POST();
    FENCE_BAR();

    // ---- P4: no reads; stage s4; MFMA Q(1,1) with held A1,B1; counted vmcnt ----
    if (s34en) stage_half(s4s, s4d, K);
    asm volatile("" ::: "memory");
    __builtin_amdgcn_s_barrier();
    __builtin_amdgcn_sched_barrier(0);
    __builtin_amdgcn_s_setprio(1);
#pragma unroll
    for (int k = 0; k < 2; k++)
#pragma unroll
        for (int ii = 0; ii < 4; ii++)
#pragma unroll
            for (int jj = 0; jj < 2; jj++)
                acc[4 + ii][1 + 2 * jj] = __builtin_amdgcn_mfma_f32_16x16x32_bf16(
                    a1[ii][k], b1[jj][k], acc[4 + ii][1 + 2 * jj], 0, 0, 0);
    __builtin_amdgcn_s_setprio(0);
    if (lastVm) { asm volatile("s_waitcnt vmcnt(0)" ::: "memory"); }
    else        { asm volatile("s_waitcnt vmcnt(4)" ::: "memory"); }
    __builtin_amdgcn_s_barrier();
}

__global__ __launch_bounds__(512, 2) void gemm256(const ushort* __restrict__ A,
                                                  const ushort* __restrict__ B,
                                                  const float* __restrict__ cosb,
                                                  const float* __restrict__ sinb,
                                                  const float* __restrict__ qnw,
                                                  const float* __restrict__ knw,
                                                  ushort* __restrict__ Qb,
                                                  ushort* __restrict__ Kb,
                                                  ushort* __restrict__ Vt,
                                                  int K) {
    __shared__ __align__(16) ushort lds[65536];   // 128 KiB
    const int tid  = threadIdx.x;
    const int wave = tid >> 6, lane = tid & 63;
    const int l16  = lane & 15, quad = lane >> 4;
    const int wm = wave >> 2, wn = wave & 3;

    // T1: XCD-aware chunked swizzle (256 blocks, 256%8==0 -> bijective).
    const int wg0 = blockIdx.x;
    const int swz = (wg0 & 7) * 32 + (wg0 >> 3);
    const int m0 = (swz >> 4) * 256, n0 = (swz & 15) * 256;

    // stage-source constants: thread tid fills LDS ushorts [tid*8, tid*8+8) of a half,
    // i.e. local row tid>>3, swizzled col -> read from inverse-swizzled global col.
    const int srow = tid >> 3;
    const int scol = ((tid & 7) * 8) ^ ((srow & 7) << 3);
    const ushort* aSrc = A + (size_t)(m0 + srow) * K + scol;
    const ushort* bSrc = B + (size_t)(n0 + srow) * K + scol;

    // ds_read constants: row = (frag base)+l16; swizzled col = ((k*4+quad)^(l16&7))*8
    const int aBase = (wm * 16 + l16) * 64;
    const int bBase = (wn * 16 + l16) * 64;
    const int cs0 = ((0 + quad) ^ (l16 & 7)) * 8;
    const int cs1 = ((4 + quad) ^ (l16 & 7)) * 8;

    f32x4 acc[8][4];
#pragma unroll
    for (int i = 0; i < 8; i++)
#pragma unroll
        for (int j = 0; j < 4; j++) acc[i][j] = (f32x4){0.f, 0.f, 0.f, 0.f};

    const int NT = K >> 6;   // K-tiles of 64

    const ushort* A0s = lds + LDSA0;
    const ushort* B0s = lds + LDSB0;
    const ushort* A1s = lds + LDSA1;
    const ushort* B1s = lds + LDSB1;

    // prologue: tile0 fully -> buf0 (8 loads), tile1 halves A0,B0 -> buf1 (4 loads)
    stage_half(aSrc,                     lds + LDSA0 + tid * 8, K);
    stage_half(aSrc + (size_t)128 * K,   lds + LDSA0 + 8192 + tid * 8, K);
    stage_half(bSrc,                     lds + LDSB0 + tid * 8, K);
    stage_half(bSrc + (size_t)128 * K,   lds + LDSB0 + 8192 + tid * 8, K);
    stage_half(aSrc + 64,                lds + LDSA1 + tid * 8, K);
    stage_half(bSrc + 64,                lds + LDSB1 + tid * 8, K);
    asm volatile("s_waitcnt vmcnt(4)" ::: "memory");   // tile0 resident; tile1 h0 in flight
    __builtin_amdgcn_s_barrier();

    for (int t = 0; t + 1 < NT; t += 2) {
        const bool s34 = (t + 2) < NT, s78 = (t + 3) < NT;
        const int k1 = (t + 1) * 64, k2 = (t + 2) * 64, k3 = (t + 3) * 64;

        ktile(A0s, B0s, acc, aBase, bBase, cs0, cs1,
              aSrc + (size_t)128 * K + k1, lds + LDSA1 + 8192 + tid * 8, true,
              bSrc + (size_t)128 * K + k1, lds + LDSB1 + 8192 + tid * 8,
              aSrc + k2,                   lds + LDSA0 + tid * 8, s34,
              bSrc + k2,                   lds + LDSB0 + tid * 8,
              K, !s34);

        ktile(A1s, B1s, acc, aBase, bBase, cs0, cs1,
              aSrc + (size_t)128 * K + k2, lds + LDSA0 + 8192 + tid * 8, s34,
              bSrc + (size_t)128 * K + k2, lds + LDSB0 + 8192 + tid * 8,
              aSrc + k3,                   lds + LDSA1 + tid * 8, s78,
              bSrc + k3,                   lds + LDSB1 + tid * 8,
              K, !s78);
    }
    // NT even here (K=2048 -> 32 tiles): no tail tile.

    // =============================== fused epilogue ===============================
    // acc[i][j][r] holds output element (row_l, col_l):
    //   row_l = (i&3)*32 + (i>>2)*128 + wm*16 + quad*4 + r   (token index within tile)
    //   col_l = (j&1)*128 + (j>>1)*64 + wn*16 + l16          (qkv channel within tile)
    // head = j&1 (2 heads per tile); d = (j>>1)*64 + wn*16 + l16; rotate-half partner
    // of (i, j, r) is (i, j+2, r) — same thread.
    const int nb = n0 >> 8;
    if (nb < 12) {
        // ---------------- Q (nb<8) or K (8<=nb<12): RMSNorm + RoPE ----------------
        const bool isQ = (nb < 8);
        const float scale = isQ ? 0.08838834764831845f : 1.0f;  // 128^-0.5 folded into Q
        const float* nw = isQ ? qnw : knw;
        const int d0 = wn * 16 + l16;            // in [0,64)
        const float w0 = nw[d0], w1 = nw[d0 + 64];
        float* fsq = (float*)lds;                // [256 rows][2 heads][4 wn] partials

        // pass 1: per-(row,head) partial sum-of-squares (this wave's 32 channels)
#pragma unroll
        for (int i = 0; i < 8; i++)
#pragma unroll
            for (int r = 0; r < 4; r++) {
                int rowl = (i & 3) * 32 + (i >> 2) * 128 + wm * 16 + quad * 4 + r;
#pragma unroll
                for (int h = 0; h < 2; h++) {
                    float x1 = acc[i][h][r], x2 = acc[i][h + 2][r];
                    float p = x1 * x1 + x2 * x2;
                    p += __shfl_xor(p, 1);
                    p += __shfl_xor(p, 2);
                    p += __shfl_xor(p, 4);
                    p += __shfl_xor(p, 8);
                    if (l16 == 0) fsq[(rowl * 2 + h) * 4 + wn] = p;
                }
            }
        __syncthreads();

        // pass 2: rstd + rope + store bf16
#pragma unroll
        for (int i = 0; i < 8; i++)
#pragma unroll
            for (int r = 0; r < 4; r++) {
                int rowl = (i & 3) * 32 + (i >> 2) * 128 + wm * 16 + quad * 4 + r;
                int tok = m0 + rowl;
                int b = tok >> 10, s = tok & 1023;
                const float* cp = cosb + (size_t)tok * HEADD;
                const float* sp = sinb + (size_t)tok * HEADD;
                float cl = cp[d0], ch = cp[d0 + 64];
                float sl = sp[d0], sh = sp[d0 + 64];
#pragma unroll
                for (int h = 0; h < 2; h++) {
                    const float* q4 = fsq + (rowl * 2 + h) * 4;
                    float ssq = q4[0] + q4[1] + q4[2] + q4[3];
                    float rstd = rsqrtf(ssq * (1.0f / 128.0f) + 1e-6f);
                    float n1 = acc[i][h][r] * rstd * w0;
                    float n2 = acc[i][h + 2][r] * rstd * w1;
                    float o1 = (n1 * cl - n2 * sl) * scale;
                    float o2 = (n2 * ch + n1 * sh) * scale;
                    ushort* dst;
                    if (isQ) {
                        int hq = (n0 >> 7) + h;
                        dst = Qb + ((size_t)((b * 16 + hq) * 1024 + s)) * HEADD;
                    } else {
                        int kv = ((n0 - 2048) >> 7) + h;
                        dst = Kb + ((size_t)((b * 8 + kv) * 1024 + s)) * HEADD;
                    }
                    dst[d0]      = f2bu(o1);
                    dst[d0 + 64] = f2bu(o2);
                }
            }
    } else {
        // ---------------- V (nb>=12): transpose via LDS -> Vt[b,kv,d,s] ----------------
        // write acc as bf16 to lds[col][row ^ ((col&7)<<3)] (256x256 = exactly 128 KiB)
#pragma unroll
        for (int i = 0; i < 8; i++)
#pragma unroll
            for (int j = 0; j < 4; j++) {
                int coll = (j & 1) * 128 + (j >> 1) * 64 + wn * 16 + l16;
                int xr = (coll & 7) << 3;
#pragma unroll
                for (int r = 0; r < 4; r++) {
                    int rowl = (i & 3) * 32 + (i >> 2) * 128 + wm * 16 + quad * 4 + r;
                    lds[coll * 256 + (rowl ^ xr)] = f2bu(acc[i][j][r]);
                }
            }
        __syncthreads();
        const int b = m0 >> 10, s0 = m0 & 1023;
        const int kv0 = (n0 - 3072) >> 7;
#pragma unroll
        for (int g = 0; g < 16; g++) {
            int gg = tid + g * 512;             // 8192 groups of 8 s-values
            int d = gg >> 5, sg = gg & 31;
            uint4 v = *(const uint4*)(lds + d * 256 + ((sg * 8) ^ ((d & 7) << 3)));
            int kv = kv0 + (d >> 7), dh = d & 127;
            *(uint4*)(Vt + ((size_t)((b * 8 + kv) * 128 + dh)) * 1024 + s0 + sg * 8) = v;
        }
    }
}

// ---------------- Wo GEMM with fused LoRA delta: C = A*B^T + A2*B2^T (fp32 out) ----------------
__global__ __launch_bounds__(256) void gemm_bt_lora(const ushort* __restrict__ A,
                                                    const ushort* __restrict__ B,
                                                    const ushort* __restrict__ A2,
                                                    const ushort* __restrict__ B2,
                                                    float* __restrict__ C) {
    __shared__ ushort As[128 * 32];
    __shared__ ushort Bs[128 * 32];
    const int tid  = threadIdx.x;
    const int wave = tid >> 6, lane = tid & 63;
    const int l16  = lane & 15, quad = lane >> 4;
    const int m0 = blockIdx.y * 128, n0 = blockIdx.x * 128;
    const int wm = (wave >> 1) * 64, wn = (wave & 1) * 64;
    const int K = DMODEL, N = DMODEL;

    f32x4 acc[4][4];
#pragma unroll
    for (int i = 0; i < 4; i++)
#pragma unroll
        for (int j = 0; j < 4; j++) acc[i][j] = (f32x4){0.f, 0.f, 0.f, 0.f};

    const int r1 = tid >> 2, kg1 = (tid & 3) * 8;
    const int r2 = (tid + 256) >> 2, kg2 = ((tid + 256) & 3) * 8;

    for (int k0 = 0; k0 < K; k0 += 32) {
        __syncthreads();
        gl_lds16(A + (size_t)(m0 + r1) * K + k0 + kg1, As + tid * 8);
        gl_lds16(B + (size_t)(n0 + r1) * K + k0 + kg1, Bs + tid * 8);
        gl_lds16(A + (size_t)(m0 + r2) * K + k0 + kg2, As + (tid + 256) * 8);
        gl_lds16(B + (size_t)(n0 + r2) * K + k0 + kg2, Bs + (tid + 256) * 8);
        __syncthreads();
        bf16x8 af[4], bfr[4];
#pragma unroll
        for (int i = 0; i < 4; i++) {
            af[i]  = *(const bf16x8*)(As + (wm + i * 16 + l16) * 32 + quad * 8);
            bfr[i] = *(const bf16x8*)(Bs + (wn + i * 16 + l16) * 32 + quad * 8);
        }
#pragma unroll
        for (int i = 0; i < 4; i++)
#pragma unroll
            for (int j = 0; j < 4; j++)
                acc[i][j] = __builtin_amdgcn_mfma_f32_16x16x32_bf16(af[i], bfr[j], acc[i][j], 0, 0, 0);
    }

    // LoRA delta: 2 extra K-steps over K2=64
#pragma unroll
    for (int k0 = 0; k0 < 64; k0 += 32) {
        __syncthreads();
        gl_lds16(A2 + (size_t)(m0 + r1) * 64 + k0 + kg1, As + tid * 8);
        gl_lds16(B2 + (size_t)(n0 + r1) * 64 + k0 + kg1, Bs + tid * 8);
        gl_lds16(A2 + (size_t)(m0 + r2) * 64 + k0 + kg2, As + (tid + 256) * 8);
        gl_lds16(B2 + (size_t)(n0 + r2) * 64 + k0 + kg2, Bs + (tid + 256) * 8);
        __syncthreads();
        bf16x8 af[4], bfr[4];
#pragma unroll
        for (int i = 0; i < 4; i++) {
            af[i]  = *(const bf16x8*)(As + (wm + i * 16 + l16) * 32 + quad * 8);
            bfr[i] = *(const bf16x8*)(Bs + (wn + i * 16 + l16) * 32 + quad * 8);
        }
#pragma unroll
        for (int i = 0; i < 4; i++)
#pragma unroll
            for (int j = 0; j < 4; j++)
                acc[i][j] = __builtin_amdgcn_mfma_f32_16x16x32_bf16(af[i], bfr[j], acc[i][j], 0, 0, 0);
    }

#pragma unroll
    for (int i = 0; i < 4; i++)
#pragma unroll
        for (int j = 0; j < 4; j++)
#pragma unroll
            for (int r = 0; r < 4; r++) {
                int m = m0 + wm + i * 16 + quad * 4 + r;
                int n = n0 + wn + j * 16 + l16;
                C[(size_t)m * N + n] = acc[i][j][r];
            }
}

// ---------------- LoRA H: G[t][e*16+r] = bf16(2*ew[t][e] * (x_t . A[e][r])) ----------------
__global__ __launch_bounds__(256) void lora_h_kernel(const ushort* __restrict__ X,
                                                     const ushort* __restrict__ Acat,
                                                     const float* __restrict__ EW,
                                                     ushort* __restrict__ G) {
    __shared__ ushort As[64 * 32];
    __shared__ ushort Bs[64 * 32];
    const int tid = threadIdx.x;
    const int wave = tid >> 6, lane = tid & 63;
    const int l16 = lane & 15, quad = lane >> 4;
    const int m0 = blockIdx.x * 64;

    f32x4 acc[4];
#pragma unroll
    for (int nt = 0; nt < 4; nt++) acc[nt] = (f32x4){0.f, 0.f, 0.f, 0.f};

    const int r1 = tid >> 2, kg1 = (tid & 3) * 8;

    for (int k0 = 0; k0 < DMODEL; k0 += 32) {
        __syncthreads();
        gl_lds16(X + (size_t)(m0 + r1) * DMODEL + k0 + kg1, As + tid * 8);
        gl_lds16(Acat + (size_t)r1 * DMODEL + k0 + kg1, Bs + tid * 8);
        __syncthreads();
        bf16x8 af = *(const bf16x8*)(As + (wave * 16 + l16) * 32 + quad * 8);
#pragma unroll
        for (int nt = 0; nt < 4; nt++) {
            bf16x8 bfr = *(const bf16x8*)(Bs + (nt * 16 + l16) * 32 + quad * 8);
            acc[nt] = __builtin_amdgcn_mfma_f32_16x16x32_bf16(af, bfr, acc[nt], 0, 0, 0);
        }
    }
#pragma unroll
    for (int nt = 0; nt < 4; nt++)
#pragma unroll
        for (int r = 0; r < 4; r++) {
            int m = m0 + wave * 16 + quad * 4 + r;
            float wsc = 2.0f * EW[(size_t)m * 4 + nt];   // LORA_SCALE=2 folded
            G[(size_t)m * 64 + nt * 16 + l16] = f2bu(acc[nt][r] * wsc);
        }
}

// ---------------- flash attention (bf16 MFMA, no-max softmax — exact by boundedness) ----------------
// |q|=|k|=sqrt(128) after rmsnorm, scale 1/sqrt(128) => |s|<=11.4, exp(s)<=9e4: fp32/bf16 safe.
#define KPITCH 136
#define VPITCH 72
__global__ __launch_bounds__(256) void fattn_kernel(const ushort* __restrict__ Qb,
                                                    const ushort* __restrict__ Kb,
                                                    const ushort* __restrict__ Vt,
                                                    __hip_bfloat16* __restrict__ O) {
    __shared__ __align__(16) ushort Ks[64 * KPITCH];
    __shared__ __align__(16) ushort Vs[128 * VPITCH];
    __shared__ __align__(16) ushort Ps[4 * 16 * VPITCH];
    const int tid = threadIdx.x;
    const int wq = tid >> 6, lane = tid & 63;
    const int l16 = lane & 15, quad = lane >> 4;
    const int qblk = 15 - (blockIdx.x >> 6);    // heavy q-blocks first
    const int bh = blockIdx.x & 63;
    const int b = bh >> 4, h = bh & 15;
    const int kvb = b * 8 + (h >> 1);
    const int q0 = qblk * 64;
    const int qbase = q0 + wq * 16;

    bf16x8 qf[4];
    const ushort* qrow = Qb + ((size_t)bh * S_LEN + qbase + l16) * HEADD;
#pragma unroll
    for (int kt = 0; kt < 4; kt++)
        qf[kt] = *(const bf16x8*)(qrow + kt * 32 + quad * 8);

    f32x4 oacc[8];
#pragma unroll
    for (int dt = 0; dt < 8; dt++) oacc[dt] = (f32x4){0.f, 0.f, 0.f, 0.f};
    float l[4] = { 0.f, 0.f, 0.f, 0.f };   // per-lane partial denominators

    const ushort* kbase = Kb + (size_t)kvb * S_LEN * HEADD;
    const ushort* vbase = Vt + (size_t)kvb * HEADD * S_LEN;
    const int ntiles = qblk + 1;

    for (int kb = 0; kb < ntiles; kb++) {
        const int k0 = kb * 64;
        __syncthreads();
        for (int c = tid; c < 1024; c += 256) {
            int row = c >> 4, col = (c & 15) * 8;
            *(uint4*)(Ks + row * KPITCH + col) =
                *(const uint4*)(kbase + (size_t)(k0 + row) * HEADD + col);
        }
        for (int c = tid; c < 1024; c += 256) {
            int row = c >> 3, col = (c & 7) * 8;
            *(uint4*)(Vs + row * VPITCH + col) =
                *(const uint4*)(vbase + (size_t)row * S_LEN + k0 + col);
        }
        __syncthreads();

        f32x4 sacc[4];
#pragma unroll
        for (int nt = 0; nt < 4; nt++) sacc[nt] = (f32x4){0.f, 0.f, 0.f, 0.f};
#pragma unroll
        for (int kt = 0; kt < 4; kt++) {
#pragma unroll
            for (int nt = 0; nt < 4; nt++) {
                bf16x8 kf = *(const bf16x8*)(Ks + (nt * 16 + l16) * KPITCH + kt * 32 + quad * 8);
                sacc[nt] = __builtin_amdgcn_mfma_f32_16x16x32_bf16(qf[kt], kf, sacc[nt], 0, 0, 0);
            }
        }

        // p = exp(s) (no max subtraction), causal mask, accumulate partial l
#pragma unroll
        for (int r = 0; r < 4; r++) {
            const int qg = qbase + quad * 4 + r;
#pragma unroll
            for (int nt = 0; nt < 4; nt++) {
                int kg = k0 + nt * 16 + l16;
                float p = (kg <= qg) ? __expf(sacc[nt][r]) : 0.f;
                l[r] += p;
                Ps[wq * 16 * VPITCH + (quad * 4 + r) * VPITCH + nt * 16 + l16] = f2bu(p);
            }
        }

        // O += P V (unnormalized, no rescale needed)
#pragma unroll
        for (int kt2 = 0; kt2 < 2; kt2++) {
            bf16x8 pf = *(const bf16x8*)(Ps + wq * 16 * VPITCH + l16 * VPITCH + kt2 * 32 + quad * 8);
#pragma unroll
            for (int dt = 0; dt < 8; dt++) {
                bf16x8 vf = *(const bf16x8*)(Vs + (dt * 16 + l16) * VPITCH + kt2 * 32 + quad * 8);
                oacc[dt] = __builtin_amdgcn_mfma_f32_16x16x32_bf16(pf, vf, oacc[dt], 0, 0, 0);
            }
        }
    }

    // epilogue: reduce l across the 16-lane key groups, normalize, store
#pragma unroll
    for (int r = 0; r < 4; r++) {
        float lr = l[r];
        lr += __shfl_xor(lr, 1);
        lr += __shfl_xor(lr, 2);
        lr += __shfl_xor(lr, 4);
        lr += __shfl_xor(lr, 8);
        float inv = 1.0f / lr;
        size_t base = ((size_t)(b * S_LEN + qbase + quad * 4 + r)) * (NHEADS * HEADD) + h * HEADD;
#pragma unroll
        for (int dt = 0; dt < 8; dt++)
            O[base + dt * 16 + l16] = __float2bfloat16(oacc[dt][r] * inv);
    }
}

extern "C" void kernel_launch(void* const* d_in, const int* in_sizes, int n_in,
                              void* d_out, int out_size, void* d_ws, size_t ws_size,
                              hipStream_t stream) {
    const float* hidden = (const float*)d_in[0];
    const float* cosb   = (const float*)d_in[1];
    const float* sinb   = (const float*)d_in[2];
    const float* Wq     = (const float*)d_in[3];
    const float* Wk     = (const float*)d_in[4];
    const float* Wv     = (const float*)d_in[5];
    const float* Wo     = (const float*)d_in[6];
    const float* qnw    = (const float*)d_in[7];
    const float* knw    = (const float*)d_in[8];
    const float* gw     = (const float*)d_in[9];
    const float* lA     = (const float*)d_in[10];
    const float* lB     = (const float*)d_in[11];
    float* out = (float*)d_out;

    // workspace layout (~105.1 MB):
    //  [0,16M):   hid_bf   (gemm256 input A — read-only during gemm256)
    //  [16M,32M): wqkv_bf  (gemm256 input B — read-only during gemm256)
    //  [32M,40M): wo_bf    (live to final gemm)
    //  [40M,56M): Qb   [56M,64M): Kb   [64M,72M): Vt   (written by gemm256 epilogue)
    //  [72M,88M): attn_bf
    //  [104M,+):  Acat 256K | Bt 256K | G 512K | ew 64K
    char* ws = (char*)d_ws;
    __hip_bfloat16* hid_bf  = (__hip_bfloat16*)ws;
    __hip_bfloat16* wqkv_bf = (__hip_bfloat16*)(ws + (16u << 20));
    __hip_bfloat16* wo_bf   = (__hip_bfloat16*)(ws + (32u << 20));
    ushort*         Qb      = (ushort*)(ws + (40u << 20));
    ushort*         Kb      = (ushort*)(ws + (56u << 20));
    ushort*         Vt      = (ushort*)(ws + (64u << 20));
    __hip_bfloat16* attn_bf = (__hip_bfloat16*)(ws + (72u << 20));
    ushort*         Acat    = (ushort*)(ws + (104u << 20));                 // 256 KB
    ushort*         Bt      = (ushort*)(ws + (104u << 20) + (256u << 10));  // 256 KB
    ushort*         G       = (ushort*)(ws + (104u << 20) + (512u << 10));  // 512 KB
    float*          ew      = (float*)(ws + (105u << 20));                  // 64 KB

    // 1. fused weight casts (Wq/Wk/Wv/Wo/lA)
    wcast_kernel<<<12416, 256, 0, stream>>>(Wq, Wk, Wv, Wo, lA,
                                            wqkv_bf, wo_bf, (__hip_bfloat16*)Acat);
    // 2. fused hidden cast + gate
    gatecast_kernel<<<4096, 256, 0, stream>>>(hidden, gw, hid_bf, ew);
    // 3. LoRA B transpose
    btrans_kernel<<<512, 256, 0, stream>>>(lB, Bt);

    // 4. fused QKV projection + RMSNorm + RoPE + V-transpose -> Qb/Kb/Vt (bf16)
    gemm256<<<256, 512, 0, stream>>>((const ushort*)hid_bf, (const ushort*)wqkv_bf,
                                     cosb, sinb, qnw, knw, Qb, Kb, Vt, DMODEL);

    // 5. flash attention -> attn_bf
    fattn_kernel<<<1024, 256, 0, stream>>>(Qb, Kb, Vt, attn_bf);

    // 6. LoRA H: G = 2*ew*(attn @ Acat^T)  (M=4096, N=64, K=2048)
    lora_h_kernel<<<64, 256, 0, stream>>>((const ushort*)attn_bf, Acat, ew, G);

    // 7. output projection + fused LoRA delta -> d_out
    gemm_bt_lora<<<dim3(16, 32), 256, 0, stream>>>((const ushort*)attn_bf, (const ushort*)wo_bf,
                                                   G, Bt, out);
}

// Round 4
// 367.970 us; speedup vs baseline: 1.1135x; 1.0177x over previous
//
#include <hip/hip_runtime.h>
#include <hip/hip_bf16.h>

// Problem constants
#define S_LEN   1024
#define BATCH   4
#define DMODEL  2048
#define NHEADS  16
#define NKVH    8
#define HEADD   128
#define NTOK    4096      // BATCH*S_LEN
#define QKV_CH  4096      // 2048 q + 1024 k + 1024 v

typedef __bf16 bf16x8 __attribute__((ext_vector_type(8)));
typedef float  f32x4  __attribute__((ext_vector_type(4)));

__device__ __forceinline__ float bf2f(unsigned short u) {
    return __uint_as_float(((unsigned)u) << 16);
}
__device__ __forceinline__ ushort f2bu(float f) {
    union { __hip_bfloat16 h; ushort u; } c;
    c.h = __float2bfloat16(f);
    return c.u;
}
// async global->LDS, 16B per lane; LDS dest must be wave-contiguous in lane order
__device__ __forceinline__ void gl_lds16(const ushort* g, ushort* l) {
    __builtin_amdgcn_global_load_lds(
        (const __attribute__((address_space(1))) void*)g,
        (__attribute__((address_space(3))) void*)l,
        16, 0, 0);
}

// ---------------- fused weight casts: Wq/Wk/Wv/Wo/lA fp32 -> bf16 ----------------
__global__ __launch_bounds__(256) void wcast_kernel(const float* __restrict__ Wq,
                                                    const float* __restrict__ Wk,
                                                    const float* __restrict__ Wv,
                                                    const float* __restrict__ Wo,
                                                    const float* __restrict__ lA,
                                                    __hip_bfloat16* __restrict__ wqkv,
                                                    __hip_bfloat16* __restrict__ wo,
                                                    __hip_bfloat16* __restrict__ acat) {
    int i = blockIdx.x * 256 + threadIdx.x;
    const float* src; __hip_bfloat16* dst; int off;
    if (i < 1048576)      { src = Wq; dst = wqkv;           off = i; }
    else if (i < 1572864) { src = Wk; dst = wqkv + 4194304; off = i - 1048576; }
    else if (i < 2097152) { src = Wv; dst = wqkv + 6291456; off = i - 1572864; }
    else if (i < 3145728) { src = Wo; dst = wo;             off = i - 2097152; }
    else if (i < 3178496) { src = lA; dst = acat;           off = i - 3145728; }
    else return;
    float4 v = ((const float4*)src)[off];
    union { ushort4 u; __hip_bfloat16 h[4]; } r;
    r.h[0] = __float2bfloat16(v.x);
    r.h[1] = __float2bfloat16(v.y);
    r.h[2] = __float2bfloat16(v.z);
    r.h[3] = __float2bfloat16(v.w);
    ((ushort4*)dst)[off] = r.u;
}

// ---------------- lB (e,d,r) fp32 -> Bt[d][e*16+r] bf16 ----------------
__global__ __launch_bounds__(256) void btrans_kernel(const float* __restrict__ lB,
                                                     ushort* __restrict__ Bt) {
    int idx = blockIdx.x * 256 + threadIdx.x;   // 131072
    int d = idx >> 6, er = idx & 63;
    int e = er >> 4, r = er & 15;
    Bt[idx] = f2bu(lB[((size_t)e * DMODEL + d) * 16 + r]);
}

// ---------------- fused hidden cast + gate (block = one token) ----------------
__global__ __launch_bounds__(256) void gatecast_kernel(const float* __restrict__ X,
                                                       const float* __restrict__ GW,
                                                       __hip_bfloat16* __restrict__ Xb,
                                                       float* __restrict__ EW) {
    __shared__ float red[4][257];
    const int t = blockIdx.x, tid = threadIdx.x;
    const float* x = X + (size_t)t * DMODEL;
    __hip_bfloat16* xb = Xb + (size_t)t * DMODEL;
    float p0 = 0.f, p1 = 0.f, p2 = 0.f, p3 = 0.f;
#pragma unroll
    for (int c = 0; c < 2; c++) {
        int i4 = tid + c * 256;           // float4 group in row
        float4 v = ((const float4*)x)[i4];
        union { ushort4 u; __hip_bfloat16 h[4]; } r;
        r.h[0] = __float2bfloat16(v.x);
        r.h[1] = __float2bfloat16(v.y);
        r.h[2] = __float2bfloat16(v.z);
        r.h[3] = __float2bfloat16(v.w);
        ((ushort4*)xb)[i4] = r.u;
        int d = i4 * 4;
        const float* g0 = GW + d;
        p0 += v.x * g0[0] + v.y * g0[1] + v.z * g0[2] + v.w * g0[3];
        const float* g1 = GW + DMODEL + d;
        p1 += v.x * g1[0] + v.y * g1[1] + v.z * g1[2] + v.w * g1[3];
        const float* g2 = GW + 2 * DMODEL + d;
        p2 += v.x * g2[0] + v.y * g2[1] + v.z * g2[2] + v.w * g2[3];
        const float* g3 = GW + 3 * DMODEL + d;
        p3 += v.x * g3[0] + v.y * g3[1] + v.z * g3[2] + v.w * g3[3];
    }
    red[0][tid] = p0; red[1][tid] = p1; red[2][tid] = p2; red[3][tid] = p3;
    __syncthreads();
    for (int s = 128; s > 0; s >>= 1) {
        if (tid < s) {
            red[0][tid] += red[0][tid + s];
            red[1][tid] += red[1][tid + s];
            red[2][tid] += red[2][tid + s];
            red[3][tid] += red[3][tid + s];
        }
        __syncthreads();
    }
    if (tid == 0) {
        float l[4] = { red[0][0], red[1][0], red[2][0], red[3][0] };
        float mx = fmaxf(fmaxf(l[0], l[1]), fmaxf(l[2], l[3]));
        float pe[4], sum = 0.f;
        for (int e = 0; e < 4; e++) { pe[e] = __expf(l[e] - mx); sum += pe[e]; }
        float inv = 1.0f / sum;
        for (int e = 0; e < 4; e++) pe[e] *= inv;
        int i1 = 0;
        for (int e = 1; e < 4; e++) if (pe[e] > pe[i1]) i1 = e;
        int i2 = -1;
        for (int e = 0; e < 4; e++) if (e != i1 && (i2 < 0 || pe[e] > pe[i2])) i2 = e;
        float o[4] = {0.f, 0.f, 0.f, 0.f};
        o[i1] = pe[i1]; o[i2] = pe[i2];
        float* ew = EW + (size_t)t * 4;
        ew[0] = o[0]; ew[1] = o[1]; ew[2] = o[2]; ew[3] = o[3];
    }
}

// =====================================================================================
// 256x256 8-phase bf16 GEMM with FUSED RMSNorm+RoPE+V-transpose epilogue.
// Round-4 fix: Q/K epilogue repacks through LDS (like V) -> 16B coalesced stores
// instead of 128 scalar 2B stores/thread (round-3's +26us tail).
// Main loop = round-2 proven schedule (frag-reuse 12/4/8/0 reads, counted vmcnt(4),
// T2 swizzle, T5 setprio, T1 XCD swizzle).
// =====================================================================================
#define LDSA0 0
#define LDSB0 16384
#define LDSA1 32768
#define LDSB1 49152

#define FENCE_BAR() do { asm volatile("" ::: "memory"); __builtin_amdgcn_s_barrier(); } while (0)

__device__ __forceinline__ void stage_half(const ushort* src, ushort* dst, int ld) {
    // half-tile = 128 rows x 64 cols bf16 = 16 KB = 2 x (512 lanes x 16 B)
    gl_lds16(src, dst);
    gl_lds16(src + (size_t)64 * ld, dst + 4096);
}

#define PHASE_MFMA_PRE()  do { \
    asm volatile("" ::: "memory"); \
    __builtin_amdgcn_s_barrier(); \
    asm volatile("s_waitcnt lgkmcnt(0)" ::: "memory"); \
    __builtin_amdgcn_sched_barrier(0); \
    __builtin_amdgcn_s_setprio(1); } while (0)

#define PHASE_MFMA_POST() do { \
    __builtin_amdgcn_s_setprio(0); } while (0)

// one K-tile (BK=64), 4 phases, fragments held in registers across phases
__device__ __forceinline__ void ktile(const ushort* As, const ushort* Bs,
                                      f32x4 (&acc)[8][4],
                                      int aBase, int bBase, int cs0, int cs1,
                                      const ushort* s1s, ushort* s1d, bool s12en,
                                      const ushort* s2s, ushort* s2d,
                                      const ushort* s3s, ushort* s3d, bool s34en,
                                      const ushort* s4s, ushort* s4d,
                                      int K, bool lastVm)
{
    bf16x8 a0[4][2], a1[4][2], b0[2][2], b1[2][2];

    // ---- P1: read A-half0 (8) + B-half0 (4); stage s1; MFMA Q(0,0) ----
#pragma unroll
    for (int ii = 0; ii < 4; ii++) {
        a0[ii][0] = *(const bf16x8*)(As + aBase + ii * 2048 + cs0);
        a0[ii][1] = *(const bf16x8*)(As + aBase + ii * 2048 + cs1);
    }
#pragma unroll
    for (int jj = 0; jj < 2; jj++) {
        b0[jj][0] = *(const bf16x8*)(Bs + bBase + jj * 4096 + cs0);
        b0[jj][1] = *(const bf16x8*)(Bs + bBase + jj * 4096 + cs1);
    }
    if (s12en) stage_half(s1s, s1d, K);
    asm volatile("s_waitcnt lgkmcnt(8)" ::: "memory");   // early-drain hint (12-read phase)
    PHASE_MFMA_PRE();
#pragma unroll
    for (int k = 0; k < 2; k++)
#pragma unroll
        for (int ii = 0; ii < 4; ii++)
#pragma unroll
            for (int jj = 0; jj < 2; jj++)
                acc[ii][2 * jj] = __builtin_amdgcn_mfma_f32_16x16x32_bf16(
                    a0[ii][k], b0[jj][k], acc[ii][2 * jj], 0, 0, 0);
    PHASE_MFMA_POST();
    FENCE_BAR();

    // ---- P2: read B-half1 (4); stage s2; MFMA Q(0,1) with held A0 ----
#pragma unroll
    for (int jj = 0; jj < 2; jj++) {
        b1[jj][0] = *(const bf16x8*)(Bs + bBase + 8192 + jj * 4096 + cs0);
        b1[jj][1] = *(const bf16x8*)(Bs + bBase + 8192 + jj * 4096 + cs1);
    }
    if (s12en) stage_half(s2s, s2d, K);
    PHASE_MFMA_PRE();
#pragma unroll
    for (int k = 0; k < 2; k++)
#pragma unroll
        for (int ii = 0; ii < 4; ii++)
#pragma unroll
            for (int jj = 0; jj < 2; jj++)
                acc[ii][1 + 2 * jj] = __builtin_amdgcn_mfma_f32_16x16x32_bf16(
                    a0[ii][k], b1[jj][k], acc[ii][1 + 2 * jj], 0, 0, 0);
    PHASE_MFMA_POST();
    FENCE_BAR();

    // ---- P3: read A-half1 (8); stage s3; MFMA Q(1,0) with held B0 ----
#pragma unroll
    for (int ii = 0; ii < 4; ii++) {
        a1[ii][0] = *(const bf16x8*)(As + aBase + 8192 + ii * 2048 + cs0);
        a1[ii][1] = *(const bf16x8*)(As + aBase + 8192 + ii * 2048 + cs1);
    }
    if (s34en) stage_half(s3s, s3d, K);
    PHASE_MFMA_PRE();
#pragma unroll
    for (int k = 0; k < 2; k++)
#pragma unroll
        for (int ii = 0; ii < 4; ii++)
#pragma unroll
            for (int jj = 0; jj < 2; jj++)
                acc[4 + ii][2 * jj] = __builtin_amdgcn_mfma_f32_16x16x32_bf16(
                    a1[ii][k], b0[jj][k], acc[4 + ii][2 * jj], 0, 0, 0);
    PHASE_MFMA_POST();
    FENCE_BAR();

    // ---- P4: no reads; stage s4; MFMA Q(1,1) with held A1,B1; counted vmcnt ----
    if (s34en) stage_half(s4s, s4d, K);
    asm volatile("" ::: "memory");
    __builtin_amdgcn_s_barrier();
    __builtin_amdgcn_sched_barrier(0);
    __builtin_amdgcn_s_setprio(1);
#pragma unroll
    for (int k = 0; k < 2; k++)
#pragma unroll
        for (int ii = 0; ii < 4; ii++)
#pragma unroll
            for (int jj = 0; jj < 2; jj++)
                acc[4 + ii][1 + 2 * jj] = __builtin_amdgcn_mfma_f32_16x16x32_bf16(
                    a1[ii][k], b1[jj][k], acc[4 + ii][1 + 2 * jj], 0, 0, 0);
    __builtin_amdgcn_s_setprio(0);
    if (lastVm) { asm volatile("s_waitcnt vmcnt(0)" ::: "memory"); }
    else        { asm volatile("s_waitcnt vmcnt(4)" ::: "memory"); }
    __builtin_amdgcn_s_barrier();
}

__global__ __launch_bounds__(512, 2) void gemm256(const ushort* __restrict__ A,
                                                  const ushort* __restrict__ B,
                                                  const float* __restrict__ cosb,
                                                  const float* __restrict__ sinb,
                                                  const float* __restrict__ qnw,
                                                  const float* __restrict__ knw,
                                                  ushort* __restrict__ Qb,
                                                  ushort* __restrict__ Kb,
                                                  ushort* __restrict__ Vt,
                                                  int K) {
    __shared__ __align__(16) ushort lds[65536];   // 128 KiB
    const int tid  = threadIdx.x;
    const int wave = tid >> 6, lane = tid & 63;
    const int l16  = lane & 15, quad = lane >> 4;
    const int wm = wave >> 2, wn = wave & 3;

    // T1: XCD-aware chunked swizzle (256 blocks, 256%8==0 -> bijective).
    const int wg0 = blockIdx.x;
    const int swz = (wg0 & 7) * 32 + (wg0 >> 3);
    const int m0 = (swz >> 4) * 256, n0 = (swz & 15) * 256;

    // stage-source constants: thread tid fills LDS ushorts [tid*8, tid*8+8) of a half,
    // i.e. local row tid>>3, swizzled col -> read from inverse-swizzled global col.
    const int srow = tid >> 3;
    const int scol = ((tid & 7) * 8) ^ ((srow & 7) << 3);
    const ushort* aSrc = A + (size_t)(m0 + srow) * K + scol;
    const ushort* bSrc = B + (size_t)(n0 + srow) * K + scol;

    // ds_read constants: row = (frag base)+l16; swizzled col = ((k*4+quad)^(l16&7))*8
    const int aBase = (wm * 16 + l16) * 64;
    const int bBase = (wn * 16 + l16) * 64;
    const int cs0 = ((0 + quad) ^ (l16 & 7)) * 8;
    const int cs1 = ((4 + quad) ^ (l16 & 7)) * 8;

    f32x4 acc[8][4];
#pragma unroll
    for (int i = 0; i < 8; i++)
#pragma unroll
        for (int j = 0; j < 4; j++) acc[i][j] = (f32x4){0.f, 0.f, 0.f, 0.f};

    const int NT = K >> 6;   // K-tiles of 64

    const ushort* A0s = lds + LDSA0;
    const ushort* B0s = lds + LDSB0;
    const ushort* A1s = lds + LDSA1;
    const ushort* B1s = lds + LDSB1;

    // prologue: tile0 fully -> buf0 (8 loads), tile1 halves A0,B0 -> buf1 (4 loads)
    stage_half(aSrc,                     lds + LDSA0 + tid * 8, K);
    stage_half(aSrc + (size_t)128 * K,   lds + LDSA0 + 8192 + tid * 8, K);
    stage_half(bSrc,                     lds + LDSB0 + tid * 8, K);
    stage_half(bSrc + (size_t)128 * K,   lds + LDSB0 + 8192 + tid * 8, K);
    stage_half(aSrc + 64,                lds + LDSA1 + tid * 8, K);
    stage_half(bSrc + 64,                lds + LDSB1 + tid * 8, K);
    asm volatile("s_waitcnt vmcnt(4)" ::: "memory");   // tile0 resident; tile1 h0 in flight
    __builtin_amdgcn_s_barrier();

    for (int t = 0; t + 1 < NT; t += 2) {
        const bool s34 = (t + 2) < NT, s78 = (t + 3) < NT;
        const int k1 = (t + 1) * 64, k2 = (t + 2) * 64, k3 = (t + 3) * 64;

        ktile(A0s, B0s, acc, aBase, bBase, cs0, cs1,
              aSrc + (size_t)128 * K + k1, lds + LDSA1 + 8192 + tid * 8, true,
              bSrc + (size_t)128 * K + k1, lds + LDSB1 + 8192 + tid * 8,
              aSrc + k2,                   lds + LDSA0 + tid * 8, s34,
              bSrc + k2,                   lds + LDSB0 + tid * 8,
              K, !s34);

        ktile(A1s, B1s, acc, aBase, bBase, cs0, cs1,
              aSrc + (size_t)128 * K + k2, lds + LDSA0 + 8192 + tid * 8, s34,
              bSrc + (size_t)128 * K + k2, lds + LDSB0 + 8192 + tid * 8,
              aSrc + k3,                   lds + LDSA1 + tid * 8, s78,
              bSrc + k3,                   lds + LDSB1 + tid * 8,
              K, !s78);
    }
    // NT even here (K=2048 -> 32 tiles): no tail tile.

    // =============================== fused epilogue ===============================
    // acc[i][j][r] holds output element (row_l, col_l):
    //   row_l = (i&3)*32 + (i>>2)*128 + wm*16 + quad*4 + r   (token index within tile)
    //   col_l = (j&1)*128 + (j>>1)*64 + wn*16 + l16          (qkv channel within tile)
    // head = j&1 (2 heads per tile); d = (j>>1)*64 + wn*16 + l16; rotate-half partner
    // of (i, j, r) is (i, j+2, r) — same thread.
    const int nb = n0 >> 8;
    if (nb < 12) {
        // ------- Q (nb<8) or K (8<=nb<12): RMSNorm + RoPE, LDS repack, 16B stores -------
        const bool isQ = (nb < 8);
        const float scale = isQ ? 0.08838834764831845f : 1.0f;  // 128^-0.5 folded into Q
        const float* nw = isQ ? qnw : knw;
        const int d0 = wn * 16 + l16;            // in [0,64)
        const float w0 = nw[d0] * scale, w1 = nw[d0 + 64] * scale;
        const int h0 = isQ ? (n0 >> 7) : ((n0 - 2048) >> 7);
        const int nh = isQ ? 16 : 8;
        ushort* gbase = isQ ? Qb : Kb;
        float* fsq = (float*)(lds + 32768);      // 4 KB at byte 64K (outside half-tile)

        // process in two 128-row halves: bf16 half-tile [128][256] at lds[0..32768)
#pragma unroll
        for (int half = 0; half < 2; half++) {
            // pass 1: per-(row,head) partial sum-of-squares (this wave's 32 channels)
#pragma unroll
            for (int i2 = 0; i2 < 4; i2++)
#pragma unroll
                for (int r = 0; r < 4; r++) {
                    const int i = half * 4 + i2;
                    const int r128 = i2 * 32 + wm * 16 + quad * 4 + r;
#pragma unroll
                    for (int h = 0; h < 2; h++) {
                        float x1 = acc[i][h][r], x2 = acc[i][h + 2][r];
                        float p = x1 * x1 + x2 * x2;
                        p += __shfl_xor(p, 1);
                        p += __shfl_xor(p, 2);
                        p += __shfl_xor(p, 4);
                        p += __shfl_xor(p, 8);
                        if (l16 == 0) fsq[(r128 * 2 + h) * 4 + wn] = p;
                    }
                }
            __syncthreads();

            // pass 2: rstd + rope -> bf16 into quad-swizzled LDS half-tile
            // swizzle: col ^ (quad<<4) — 4 quads hit 4 disjoint 32B sub-blocks
            // of each 128B bank window -> conflict-free ds_write_b16.
#pragma unroll
            for (int i2 = 0; i2 < 4; i2++)
#pragma unroll
                for (int r = 0; r < 4; r++) {
                    const int i = half * 4 + i2;
                    const int r128 = i2 * 32 + wm * 16 + quad * 4 + r;
                    const int tok = m0 + half * 128 + r128;
                    const float* cp = cosb + (size_t)tok * HEADD;
                    const float* sp = sinb + (size_t)tok * HEADD;
                    float cl = cp[d0], ch = cp[d0 + 64];
                    float sl = sp[d0], sh = sp[d0 + 64];
                    const int sw = ((r128 >> 2) & 3) << 4;
                    ushort* lrow = lds + r128 * 256;
#pragma unroll
                    for (int h = 0; h < 2; h++) {
                        const float* q4 = fsq + (r128 * 2 + h) * 4;
                        float ssq = q4[0] + q4[1] + q4[2] + q4[3];
                        float rstd = rsqrtf(ssq * (1.0f / 128.0f) + 1e-6f);
                        float n1 = acc[i][h][r] * rstd * w0;
                        float n2 = acc[i][h + 2][r] * rstd * w1;
                        lrow[(h * 128 + d0) ^ sw]      = f2bu(n1 * cl - n2 * sl);
                        lrow[(h * 128 + d0 + 64) ^ sw] = f2bu(n2 * ch + n1 * sh);
                    }
                }
            __syncthreads();

            // coalesced store: 128 rows x 256 cols = 4096 uint4 groups, 8/thread
#pragma unroll
            for (int g = 0; g < 8; g++) {
                int gg = tid + g * 512;
                int row = gg >> 5, colg = gg & 31;
                int col8 = colg * 8;
                int sw = ((row >> 2) & 3) << 4;
                uint4 v = *(const uint4*)(lds + row * 256 + (col8 ^ sw));
                int head = col8 >> 7, d = col8 & 127;
                int tok = m0 + half * 128 + row;
                int b = tok >> 10, s = tok & 1023;
                *(uint4*)(gbase + ((size_t)((b * nh + h0 + head) * 1024 + s)) * HEADD + d) = v;
            }
            __syncthreads();
        }
    } else {
        // ---------------- V (nb>=12): transpose via LDS -> Vt[b,kv,d,s] ----------------
        // write acc as bf16 to lds[col][row ^ ((col&7)<<3)] (256x256 = exactly 128 KiB)
#pragma unroll
        for (int i = 0; i < 8; i++)
#pragma unroll
            for (int j = 0; j < 4; j++) {
                int coll = (j & 1) * 128 + (j >> 1) * 64 + wn * 16 + l16;
                int xr = (coll & 7) << 3;
#pragma unroll
                for (int r = 0; r < 4; r++) {
                    int rowl = (i & 3) * 32 + (i >> 2) * 128 + wm * 16 + quad * 4 + r;
                    lds[coll * 256 + (rowl ^ xr)] = f2bu(acc[i][j][r]);
                }
            }
        __syncthreads();
        const int b = m0 >> 10, s0 = m0 & 1023;
        const int kv0 = (n0 - 3072) >> 7;
#pragma unroll
        for (int g = 0; g < 16; g++) {
            int gg = tid + g * 512;             // 8192 groups of 8 s-values
            int d = gg >> 5, sg = gg & 31;
            uint4 v = *(const uint4*)(lds + d * 256 + ((sg * 8) ^ ((d & 7) << 3)));
            int kv = kv0 + (d >> 7), dh = d & 127;
            *(uint4*)(Vt + ((size_t)((b * 8 + kv) * 128 + dh)) * 1024 + s0 + sg * 8) = v;
        }
    }
}

// ---------------- Wo GEMM with fused LoRA delta: C = A*B^T + A2*B2^T (fp32 out) ----------------
__global__ __launch_bounds__(256) void gemm_bt_lora(const ushort* __restrict__ A,
                                                    const ushort* __restrict__ B,
                                                    const ushort* __restrict__ A2,
                                                    const ushort* __restrict__ B2,
                                                    float* __restrict__ C) {
    __shared__ ushort As[128 * 32];
    __shared__ ushort Bs[128 * 32];
    const int tid  = threadIdx.x;
    const int wave = tid >> 6, lane = tid & 63;
    const int l16  = lane & 15, quad = lane >> 4;
    const int m0 = blockIdx.y * 128, n0 = blockIdx.x * 128;
    const int wm = (wave >> 1) * 64, wn = (wave & 1) * 64;
    const int K = DMODEL, N = DMODEL;

    f32x4 acc[4][4];
#pragma unroll
    for (int i = 0; i < 4; i++)
#pragma unroll
        for (int j = 0; j < 4; j++) acc[i][j] = (f32x4){0.f, 0.f, 0.f, 0.f};

    const int r1 = tid >> 2, kg1 = (tid & 3) * 8;
    const int r2 = (tid + 256) >> 2, kg2 = ((tid + 256) & 3) * 8;

    for (int k0 = 0; k0 < K; k0 += 32) {
        __syncthreads();
        gl_lds16(A + (size_t)(m0 + r1) * K + k0 + kg1, As + tid * 8);
        gl_lds16(B + (size_t)(n0 + r1) * K + k0 + kg1, Bs + tid * 8);
        gl_lds16(A + (size_t)(m0 + r2) * K + k0 + kg2, As + (tid + 256) * 8);
        gl_lds16(B + (size_t)(n0 + r2) * K + k0 + kg2, Bs + (tid + 256) * 8);
        __syncthreads();
        bf16x8 af[4], bfr[4];
#pragma unroll
        for (int i = 0; i < 4; i++) {
            af[i]  = *(const bf16x8*)(As + (wm + i * 16 + l16) * 32 + quad * 8);
            bfr[i] = *(const bf16x8*)(Bs + (wn + i * 16 + l16) * 32 + quad * 8);
        }
#pragma unroll
        for (int i = 0; i < 4; i++)
#pragma unroll
            for (int j = 0; j < 4; j++)
                acc[i][j] = __builtin_amdgcn_mfma_f32_16x16x32_bf16(af[i], bfr[j], acc[i][j], 0, 0, 0);
    }

    // LoRA delta: 2 extra K-steps over K2=64
#pragma unroll
    for (int k0 = 0; k0 < 64; k0 += 32) {
        __syncthreads();
        gl_lds16(A2 + (size_t)(m0 + r1) * 64 + k0 + kg1, As + tid * 8);
        gl_lds16(B2 + (size_t)(n0 + r1) * 64 + k0 + kg1, Bs + tid * 8);
        gl_lds16(A2 + (size_t)(m0 + r2) * 64 + k0 + kg2, As + (tid + 256) * 8);
        gl_lds16(B2 + (size_t)(n0 + r2) * 64 + k0 + kg2, Bs + (tid + 256) * 8);
        __syncthreads();
        bf16x8 af[4], bfr[4];
#pragma unroll
        for (int i = 0; i < 4; i++) {
            af[i]  = *(const bf16x8*)(As + (wm + i * 16 + l16) * 32 + quad * 8);
            bfr[i] = *(const bf16x8*)(Bs + (wn + i * 16 + l16) * 32 + quad * 8);
        }
#pragma unroll
        for (int i = 0; i < 4; i++)
#pragma unroll
            for (int j = 0; j < 4; j++)
                acc[i][j] = __builtin_amdgcn_mfma_f32_16x16x32_bf16(af[i], bfr[j], acc[i][j], 0, 0, 0);
    }

#pragma unroll
    for (int i = 0; i < 4; i++)
#pragma unroll
        for (int j = 0; j < 4; j++)
#pragma unroll
            for (int r = 0; r < 4; r++) {
                int m = m0 + wm + i * 16 + quad * 4 + r;
                int n = n0 + wn + j * 16 + l16;
                C[(size_t)m * N + n] = acc[i][j][r];
            }
}

// ---------------- LoRA H: G[t][e*16+r] = bf16(2*ew[t][e] * (x_t . A[e][r])) ----------------
__global__ __launch_bounds__(256) void lora_h_kernel(const ushort* __restrict__ X,
                                                     const ushort* __restrict__ Acat,
                                                     const float* __restrict__ EW,
                                                     ushort* __restrict__ G) {
    __shared__ ushort As[64 * 32];
    __shared__ ushort Bs[64 * 32];
    const int tid = threadIdx.x;
    const int wave = tid >> 6, lane = tid & 63;
    const int l16 = lane & 15, quad = lane >> 4;
    const int m0 = blockIdx.x * 64;

    f32x4 acc[4];
#pragma unroll
    for (int nt = 0; nt < 4; nt++) acc[nt] = (f32x4){0.f, 0.f, 0.f, 0.f};

    const int r1 = tid >> 2, kg1 = (tid & 3) * 8;

    for (int k0 = 0; k0 < DMODEL; k0 += 32) {
        __syncthreads();
        gl_lds16(X + (size_t)(m0 + r1) * DMODEL + k0 + kg1, As + tid * 8);
        gl_lds16(Acat + (size_t)r1 * DMODEL + k0 + kg1, Bs + tid * 8);
        __syncthreads();
        bf16x8 af = *(const bf16x8*)(As + (wave * 16 + l16) * 32 + quad * 8);
#pragma unroll
        for (int nt = 0; nt < 4; nt++) {
            bf16x8 bfr = *(const bf16x8*)(Bs + (nt * 16 + l16) * 32 + quad * 8);
            acc[nt] = __builtin_amdgcn_mfma_f32_16x16x32_bf16(af, bfr, acc[nt], 0, 0, 0);
        }
    }
#pragma unroll
    for (int nt = 0; nt < 4; nt++)
#pragma unroll
        for (int r = 0; r < 4; r++) {
            int m = m0 + wave * 16 + quad * 4 + r;
            float wsc = 2.0f * EW[(size_t)m * 4 + nt];   // LORA_SCALE=2 folded
            G[(size_t)m * 64 + nt * 16 + l16] = f2bu(acc[nt][r] * wsc);
        }
}

// ---------------- flash attention (bf16 MFMA, no-max softmax — exact by boundedness) ----------------
// |q|=|k|=sqrt(128) after rmsnorm, scale 1/sqrt(128) => |s|<=11.4, exp(s)<=9e4: fp32/bf16 safe.
#define KPITCH 136
#define VPITCH 72
__global__ __launch_bounds__(256) void fattn_kernel(const ushort* __restrict__ Qb,
                                                    const ushort* __restrict__ Kb,
                                                    const ushort* __restrict__ Vt,
                                                    __hip_bfloat16* __restrict__ O) {
    __shared__ __align__(16) ushort Ks[64 * KPITCH];
    __shared__ __align__(16) ushort Vs[128 * VPITCH];
    __shared__ __align__(16) ushort Ps[4 * 16 * VPITCH];
    const int tid = threadIdx.x;
    const int wq = tid >> 6, lane = tid & 63;
    const int l16 = lane & 15, quad = lane >> 4;
    const int qblk = 15 - (blockIdx.x >> 6);    // heavy q-blocks first
    const int bh = blockIdx.x & 63;
    const int b = bh >> 4, h = bh & 15;
    const int kvb = b * 8 + (h >> 1);
    const int q0 = qblk * 64;
    const int qbase = q0 + wq * 16;

    bf16x8 qf[4];
    const ushort* qrow = Qb + ((size_t)bh * S_LEN + qbase + l16) * HEADD;
#pragma unroll
    for (int kt = 0; kt < 4; kt++)
        qf[kt] = *(const bf16x8*)(qrow + kt * 32 + quad * 8);

    f32x4 oacc[8];
#pragma unroll
    for (int dt = 0; dt < 8; dt++) oacc[dt] = (f32x4){0.f, 0.f, 0.f, 0.f};
    float l[4] = { 0.f, 0.f, 0.f, 0.f };   // per-lane partial denominators

    const ushort* kbase = Kb + (size_t)kvb * S_LEN * HEADD;
    const ushort* vbase = Vt + (size_t)kvb * HEADD * S_LEN;
    const int ntiles = qblk + 1;

    for (int kb = 0; kb < ntiles; kb++) {
        const int k0 = kb * 64;
        __syncthreads();
        for (int c = tid; c < 1024; c += 256) {
            int row = c >> 4, col = (c & 15) * 8;
            *(uint4*)(Ks + row * KPITCH + col) =
                *(const uint4*)(kbase + (size_t)(k0 + row) * HEADD + col);
        }
        for (int c = tid; c < 1024; c += 256) {
            int row = c >> 3, col = (c & 7) * 8;
            *(uint4*)(Vs + row * VPITCH + col) =
                *(const uint4*)(vbase + (size_t)row * S_LEN + k0 + col);
        }
        __syncthreads();

        f32x4 sacc[4];
#pragma unroll
        for (int nt = 0; nt < 4; nt++) sacc[nt] = (f32x4){0.f, 0.f, 0.f, 0.f};
#pragma unroll
        for (int kt = 0; kt < 4; kt++) {
#pragma unroll
            for (int nt = 0; nt < 4; nt++) {
                bf16x8 kf = *(const bf16x8*)(Ks + (nt * 16 + l16) * KPITCH + kt * 32 + quad * 8);
                sacc[nt] = __builtin_amdgcn_mfma_f32_16x16x32_bf16(qf[kt], kf, sacc[nt], 0, 0, 0);
            }
        }

        // p = exp(s) (no max subtraction), causal mask, accumulate partial l
#pragma unroll
        for (int r = 0; r < 4; r++) {
            const int qg = qbase + quad * 4 + r;
#pragma unroll
            for (int nt = 0; nt < 4; nt++) {
                int kg = k0 + nt * 16 + l16;
                float p = (kg <= qg) ? __expf(sacc[nt][r]) : 0.f;
                l[r] += p;
                Ps[wq * 16 * VPITCH + (quad * 4 + r) * VPITCH + nt * 16 + l16] = f2bu(p);
            }
        }

        // O += P V (unnormalized, no rescale needed)
#pragma unroll
        for (int kt2 = 0; kt2 < 2; kt2++) {
            bf16x8 pf = *(const bf16x8*)(Ps + wq * 16 * VPITCH + l16 * VPITCH + kt2 * 32 + quad * 8);
#pragma unroll
            for (int dt = 0; dt < 8; dt++) {
                bf16x8 vf = *(const bf16x8*)(Vs + (dt * 16 + l16) * VPITCH + kt2 * 32 + quad * 8);
                oacc[dt] = __builtin_amdgcn_mfma_f32_16x16x32_bf16(pf, vf, oacc[dt], 0, 0, 0);
            }
        }
    }

    // epilogue: reduce l across the 16-lane key groups, normalize, store
#pragma unroll
    for (int r = 0; r < 4; r++) {
        float lr = l[r];
        lr += __shfl_xor(lr, 1);
        lr += __shfl_xor(lr, 2);
        lr += __shfl_xor(lr, 4);
        lr += __shfl_xor(lr, 8);
        float inv = 1.0f / lr;
        size_t base = ((size_t)(b * S_LEN + qbase + quad * 4 + r)) * (NHEADS * HEADD) + h * HEADD;
#pragma unroll
        for (int dt = 0; dt < 8; dt++)
            O[base + dt * 16 + l16] = __float2bfloat16(oacc[dt][r] * inv);
    }
}

extern "C" void kernel_launch(void* const* d_in, const int* in_sizes, int n_in,
                              void* d_out, int out_size, void* d_ws, size_t ws_size,
                              hipStream_t stream) {
    const float* hidden = (const float*)d_in[0];
    const float* cosb   = (const float*)d_in[1];
    const float* sinb   = (const float*)d_in[2];
    const float* Wq     = (const float*)d_in[3];
    const float* Wk     = (const float*)d_in[4];
    const float* Wv     = (const float*)d_in[5];
    const float* Wo     = (const float*)d_in[6];
    const float* qnw    = (const float*)d_in[7];
    const float* knw    = (const float*)d_in[8];
    const float* gw     = (const float*)d_in[9];
    const float* lA     = (const float*)d_in[10];
    const float* lB     = (const float*)d_in[11];
    float* out = (float*)d_out;

    // workspace layout (~105.1 MB):
    //  [0,16M):   hid_bf   (gemm256 input A — read-only during gemm256)
    //  [16M,32M): wqkv_bf  (gemm256 input B — read-only during gemm256)
    //  [32M,40M): wo_bf    (live to final gemm)
    //  [40M,56M): Qb   [56M,64M): Kb   [64M,72M): Vt   (written by gemm256 epilogue)
    //  [72M,88M): attn_bf
    //  [104M,+):  Acat 256K | Bt 256K | G 512K | ew 64K
    char* ws = (char*)d_ws;
    __hip_bfloat16* hid_bf  = (__hip_bfloat16*)ws;
    __hip_bfloat16* wqkv_bf = (__hip_bfloat16*)(ws + (16u << 20));
    __hip_bfloat16* wo_bf   = (__hip_bfloat16*)(ws + (32u << 20));
    ushort*         Qb      = (ushort*)(ws + (40u << 20));
    ushort*         Kb      = (ushort*)(ws + (56u << 20));
    ushort*         Vt      = (ushort*)(ws + (64u << 20));
    __hip_bfloat16* attn_bf = (__hip_bfloat16*)(ws + (72u << 20));
    ushort*         Acat    = (ushort*)(ws + (104u << 20));                 // 256 KB
    ushort*         Bt      = (ushort*)(ws + (104u << 20) + (256u << 10));  // 256 KB
    ushort*         G       = (ushort*)(ws + (104u << 20) + (512u << 10));  // 512 KB
    float*          ew      = (float*)(ws + (105u << 20));                  // 64 KB

    // 1. fused weight casts (Wq/Wk/Wv/Wo/lA)
    wcast_kernel<<<12416, 256, 0, stream>>>(Wq, Wk, Wv, Wo, lA,
                                            wqkv_bf, wo_bf, (__hip_bfloat16*)Acat);
    // 2. fused hidden cast + gate
    gatecast_kernel<<<4096, 256, 0, stream>>>(hidden, gw, hid_bf, ew);
    // 3. LoRA B transpose
    btrans_kernel<<<512, 256, 0, stream>>>(lB, Bt);

    // 4. fused QKV projection + RMSNorm + RoPE + V-transpose -> Qb/Kb/Vt (bf16)
    gemm256<<<256, 512, 0, stream>>>((const ushort*)hid_bf, (const ushort*)wqkv_bf,
                                     cosb, sinb, qnw, knw, Qb, Kb, Vt, DMODEL);

    // 5. flash attention -> attn_bf
    fattn_kernel<<<1024, 256, 0, stream>>>(Qb, Kb, Vt, attn_bf);

    // 6. LoRA H: G = 2*ew*(attn @ Acat^T)  (M=4096, N=64, K=2048)
    lora_h_kernel<<<64, 256, 0, stream>>>((const ushort*)attn_bf, Acat, ew, G);

    // 7. output projection + fused LoRA delta -> d_out
    gemm_bt_lora<<<dim3(16, 32), 256, 0, stream>>>((const ushort*)attn_bf, (const ushort*)wo_bf,
                                                   G, Bt, out);
}